// Round 8
// baseline (2450.869 us; speedup 1.0000x reference)
//
#include <hip/hip_runtime.h>
#include <hip/hip_bf16.h>

#define N_  64
#define T_  512
#define D_  512
#define H_  512
#define FH  2048   // 4H
#define K1  1024   // hi|lo packed columns
#define NWG 256
#define NSTEP 128
#define NHELP 128
#define BLK 256

typedef __attribute__((ext_vector_type(4))) float f32x4;
typedef __attribute__((ext_vector_type(8))) short bf16x8;

__device__ __forceinline__ unsigned short f2bf(float f) {
  unsigned u = __float_as_uint(f);
  return (unsigned short)((u + 0x7FFFu + ((u >> 16) & 1u)) >> 16);
}
__device__ __forceinline__ float bf2f(unsigned short s) {
  return __uint_as_float(((unsigned)s) << 16);
}
__device__ __forceinline__ float sigf(float x) {
  return 1.0f / (1.0f + __expf(-x));
}
__device__ __forceinline__ float tanhft(float x) {  // branch-free tanh
  x = fminf(15.f, fmaxf(-15.f, x));
  float e = __expf(2.f * x);
  return (e - 1.f) / (e + 1.f);
}

__device__ __forceinline__ void gl_lds16(const void* g, void* l) {
  __builtin_amdgcn_global_load_lds(
      (const __attribute__((address_space(1))) void*)g,
      (__attribute__((address_space(3))) void*)l, 16, 0, 0);
}

// LLC-coherent ops (sc0 sc1): proven cross-XCD handoff path (R5/R7).
__device__ __forceinline__ bf16x8 ld16cc(const short* p) {
  bf16x8 d;
  asm volatile("global_load_dwordx4 %0, %1, off sc0 sc1" : "=v"(d) : "v"(p));
  return d;
}
__device__ __forceinline__ void st4cc(short* p, unsigned v) {
  asm volatile("global_store_dword %0, %1, off sc0 sc1" ::"v"(p), "v"(v)
               : "memory");
}
__device__ __forceinline__ unsigned ldflag(const unsigned* p) {
  unsigned v;
  asm volatile("global_load_dword %0, %1, off sc0 sc1\ns_waitcnt vmcnt(0)"
               : "=v"(v) : "v"(p) : "memory");
  return v;
}
__device__ __forceinline__ void stflag(unsigned* p, unsigned v) {
  asm volatile("global_store_dword %0, %1, off sc0 sc1" ::"v"(p), "v"(v)
               : "memory");
}

// Grid barrier over 256 WGs (prologue only): slot arrival + WG0 poller.
template <int SLP>
__device__ __forceinline__ void gbar2(unsigned* arr, unsigned* rel,
                                      unsigned gen, int wg) {
  __syncthreads();
  const int tid = threadIdx.x;
  if (tid == 0) {
    __builtin_amdgcn_fence(__ATOMIC_RELEASE, "agent");
    __hip_atomic_store(&arr[wg], gen, __ATOMIC_RELAXED,
                       __HIP_MEMORY_SCOPE_AGENT);
  }
  if (wg == 0) {
    if (tid < 64) {
      int guard = 0;
      for (;;) {
        unsigned v0 = __hip_atomic_load(&arr[tid], __ATOMIC_RELAXED,
                                        __HIP_MEMORY_SCOPE_AGENT);
        unsigned v1 = __hip_atomic_load(&arr[tid + 64], __ATOMIC_RELAXED,
                                        __HIP_MEMORY_SCOPE_AGENT);
        unsigned v2 = __hip_atomic_load(&arr[tid + 128], __ATOMIC_RELAXED,
                                        __HIP_MEMORY_SCOPE_AGENT);
        unsigned v3 = __hip_atomic_load(&arr[tid + 192], __ATOMIC_RELAXED,
                                        __HIP_MEMORY_SCOPE_AGENT);
        if (__all(v0 >= gen && v1 >= gen && v2 >= gen && v3 >= gen)) break;
        __builtin_amdgcn_s_sleep(SLP);
        if (++guard > (1 << 20)) break;
      }
    }
    __syncthreads();
    if (tid == 0)
      __hip_atomic_store(rel, gen, __ATOMIC_RELAXED, __HIP_MEMORY_SCOPE_AGENT);
  } else if (tid == 0) {
    int guard = 0;
    while (__hip_atomic_load(rel, __ATOMIC_RELAXED,
                             __HIP_MEMORY_SCOPE_AGENT) < gen) {
      __builtin_amdgcn_s_sleep(SLP);
      if (++guard > (1 << 20)) break;
    }
  }
  if (tid == 0) __builtin_amdgcn_fence(__ATOMIC_ACQUIRE, "agent");
  __syncthreads();
}

// Helper-group barrier (128 helper WGs); poller hid==0.
template <int SLP>
__device__ __forceinline__ void hbar(unsigned* arr, unsigned* rel,
                                     unsigned gen, int hid) {
  __syncthreads();
  const int tid = threadIdx.x;
  if (tid == 0) {
    __builtin_amdgcn_fence(__ATOMIC_RELEASE, "agent");
    __hip_atomic_store(&arr[hid], gen, __ATOMIC_RELAXED,
                       __HIP_MEMORY_SCOPE_AGENT);
  }
  if (hid == 0) {
    if (tid < 64) {
      int guard = 0;
      for (;;) {
        unsigned v0 = __hip_atomic_load(&arr[tid], __ATOMIC_RELAXED,
                                        __HIP_MEMORY_SCOPE_AGENT);
        unsigned v1 = __hip_atomic_load(&arr[tid + 64], __ATOMIC_RELAXED,
                                        __HIP_MEMORY_SCOPE_AGENT);
        if (__all(v0 >= gen && v1 >= gen)) break;
        __builtin_amdgcn_s_sleep(SLP);
        if (++guard > (1 << 20)) break;
      }
    }
    __syncthreads();
    if (tid == 0)
      __hip_atomic_store(rel, gen, __ATOMIC_RELAXED, __HIP_MEMORY_SCOPE_AGENT);
  } else if (tid == 0) {
    int guard = 0;
    while (__hip_atomic_load(rel, __ATOMIC_RELAXED,
                             __HIP_MEMORY_SCOPE_AGENT) < gen) {
      __builtin_amdgcn_s_sleep(SLP);
      if (++guard > (1 << 20)) break;
    }
  }
  if (tid == 0) __builtin_amdgcn_fence(__ATOMIC_ACQUIRE, "agent");
  __syncthreads();
}

// x chunk -> hi/lo bf16 (octet-wise coalesced)
__device__ __forceinline__ void convert_x(const float* __restrict__ x,
                                          short* __restrict__ xprim, int t0,
                                          int Mch, int idx0, int stride) {
  for (int idx = idx0; idx < Mch * 64; idx += stride) {
    int mrow = idx >> 6, oct = idx & 63;
    int tl = mrow >> 6, n = mrow & 63;
    const float* src = x + ((size_t)n * T_ + (t0 + tl)) * D_ + oct * 8;
    bf16x8 hv, lv;
#pragma unroll
    for (int i = 0; i < 8; ++i) {
      float v = src[i];
      unsigned short h = f2bf(v);
      hv[i] = (short)h;
      lv[i] = (short)f2bf(v - bf2f(h));
    }
    *(bf16x8*)(xprim + (size_t)mrow * K1 + oct * 8) = hv;
    *(bf16x8*)(xprim + (size_t)mrow * K1 + 512 + oct * 8) = lv;
  }
}

// Phase-1 GEMM: xw = x' @ Wx' + b (128x128 tiles, K'=1536, split-bf16)
__device__ __forceinline__ void phase1(const short* __restrict__ xprim,
                                       const short* __restrict__ Wxt,
                                       const float* __restrict__ b,
                                       float* __restrict__ xw, int nTiles,
                                       int tile0, int tstride, short* Asm,
                                       short* Bsm) {
  const int tid = threadIdx.x;
  const int lane = tid & 63, wv = tid >> 6;
  const int wm = wv >> 1, wn = wv & 1;
  const int sslot = (lane & 3) ^ ((lane >> 3) & 3);
  for (int tile = tile0; tile < nTiles; tile += tstride) {
    int tm = tile >> 4, tn = tile & 15;
    int m0 = tm << 7, n0 = tn << 7;
    f32x4 acc[4][4];
    for (int i = 0; i < 4; ++i)
      for (int j = 0; j < 4; ++j) acc[i][j] = (f32x4){0.f, 0.f, 0.f, 0.f};
    for (int kk = 0; kk < 48; ++kk) {
      int ac = (kk < 16 ? kk : kk - 16) << 5;
      int bc = (kk < 32 ? kk : kk - 32) << 5;
      __syncthreads();
      {
        const short* sa =
            xprim + (size_t)(m0 + wv * 32 + (lane >> 2)) * K1 + ac + sslot * 8;
        gl_lds16(sa, Asm + (wv * 32) * 32);
        gl_lds16(sa + (size_t)16 * K1, Asm + (wv * 32 + 16) * 32);
        const short* sb =
            Wxt + (size_t)(n0 + wv * 32 + (lane >> 2)) * K1 + bc + sslot * 8;
        gl_lds16(sb, Bsm + (wv * 32) * 32);
        gl_lds16(sb + (size_t)16 * K1, Bsm + (wv * 32 + 16) * 32);
      }
      __syncthreads();
      bf16x8 af[4], bfr[4];
      for (int mi = 0; mi < 4; ++mi) {
        int R = wm * 64 + mi * 16 + (lane & 15);
        int rs = ((lane >> 4) & 3) ^ ((R >> 1) & 3);
        af[mi] = *(const bf16x8*)(Asm + R * 32 + rs * 8);
      }
      for (int ni = 0; ni < 4; ++ni) {
        int R = wn * 64 + ni * 16 + (lane & 15);
        int rs = ((lane >> 4) & 3) ^ ((R >> 1) & 3);
        bfr[ni] = *(const bf16x8*)(Bsm + R * 32 + rs * 8);
      }
      for (int mi = 0; mi < 4; ++mi)
        for (int ni = 0; ni < 4; ++ni)
          acc[mi][ni] = __builtin_amdgcn_mfma_f32_16x16x32_bf16(
              af[mi], bfr[ni], acc[mi][ni], 0, 0, 0);
    }
    for (int ni = 0; ni < 4; ++ni) {
      float bj = b[n0 + wn * 64 + ni * 16 + (lane & 15)];
      for (int mi = 0; mi < 4; ++mi) {
        int mg = m0 + wm * 64 + mi * 16 + ((lane >> 4) << 2);
        float* dst = xw + (size_t)mg * FH + n0 + wn * 64 + ni * 16 + (lane & 15);
        for (int r = 0; r < 4; ++r) dst[(size_t)r * FH] = acc[mi][ni][r] + bj;
      }
    }
  }
}

// Recurrent steps. h via LLC sc0sc1; c in a register; xr prefetched
// post-publish so the poll's vmcnt(0) never waits on gate inputs.
template <bool LWH>
__device__ __forceinline__ void run_steps(
    int rb, int cg, int t0, int Tc, unsigned& fl, float& creg,
    const short* wlds, const short* __restrict__ Wht, short* hbuf0,
    short* hbuf1, const float* __restrict__ xw, float* __restrict__ out,
    unsigned* arrH, short* hst, float (*glds)[16][16]) {
  const int tid = threadIdx.x;
  const int lane = tid & 63, wv = tid >> 6;
  const int lc = wv * 16 + (lane & 15);
  const int gcl = wv * 512 + cg * 16 + (lane & 15);
  const int row = tid >> 4, col = tid & 15;
  const int n = rb * 16 + row, jh = cg * 16 + col;
  unsigned* myflag = &arrH[rb * 64 + cg];
  unsigned* grp = &arrH[rb * 64];

  // gate inputs for step 0 of this chunk
  const float* xr0 = xw + ((size_t)n) * FH + jh;
  float x0 = xr0[0], x1 = xr0[512], x2 = xr0[1024], x3 = xr0[1536];

  for (int tl = 0; tl < Tc; ++tl) {
    const int tg = t0 + tl;
    if (wv == 0) {
      int guard = 0;
      for (;;) {
        unsigned v = ldflag(grp + (lane & 31));
        if (__all(v >= fl)) break;
        __builtin_amdgcn_s_sleep(1);
        if (++guard > (1 << 20)) break;
      }
    }
    __syncthreads();
    const short* hc = (tg & 1) ? hbuf1 : hbuf0;
    short* hn = (tg & 1) ? hbuf0 : hbuf1;

    // ---- stage hi-half: row r=i*4+wv uniform per instr, octet c=lane ----
    // global: lane-contiguous 1KB per instr; LDS slots = lane^(r&7): all 64
    // distinct -> conflict-free writes; reads keep the XOR (2-way, free).
    bf16x8 tmp[4];
#pragma unroll
    for (int i = 0; i < 4; ++i) {
      int r = i * 4 + wv;
      tmp[i] = ld16cc(hc + (size_t)(rb * 16 + r) * K1 + lane * 8);
    }
    asm volatile("s_waitcnt vmcnt(0)" ::: "memory");
    __builtin_amdgcn_sched_barrier(0);
#pragma unroll
    for (int i = 0; i < 4; ++i) {
      int r = i * 4 + wv;
      *(bf16x8*)(hst + r * 512 + ((lane ^ (r & 7)) << 3)) = tmp[i];
    }
    __syncthreads();
    bf16x8 af[16];
#pragma unroll
    for (int kk = 0; kk < 16; ++kk) {
      int c = kk * 4 + (lane >> 4), r = lane & 15;
      af[kk] = *(const bf16x8*)(hst + r * 512 + ((c ^ (r & 7)) << 3));
    }
    __syncthreads();  // hst free for lo

    // issue lo-half loads; latency hides under the 32 hi MFMAs
    bf16x8 tlo[4];
#pragma unroll
    for (int i = 0; i < 4; ++i) {
      int r = i * 4 + wv;
      tlo[i] = ld16cc(hc + (size_t)(rb * 16 + r) * K1 + 512 + lane * 8);
    }
    f32x4 acc0 = {0.f, 0.f, 0.f, 0.f};
    f32x4 acc1 = {0.f, 0.f, 0.f, 0.f};
#pragma unroll
    for (int kk = 0; kk < 32; ++kk) {  // A-hi x (B-hi | B-lo)
      bf16x8 bv;
      if constexpr (LWH) {
        int k16 = 4 * kk + (lane >> 4);
        bv = *(const bf16x8*)(wlds + lc * K1 + ((k16 ^ (lc & 7)) << 3));
      } else {
        bv = *(const bf16x8*)(Wht + (size_t)gcl * K1 + kk * 32 + (lane >> 4) * 8);
      }
      if (kk & 1)
        acc1 = __builtin_amdgcn_mfma_f32_16x16x32_bf16(af[kk & 15], bv, acc1,
                                                       0, 0, 0);
      else
        acc0 = __builtin_amdgcn_mfma_f32_16x16x32_bf16(af[kk & 15], bv, acc0,
                                                       0, 0, 0);
    }
    asm volatile("s_waitcnt vmcnt(0)" ::: "memory");
    __builtin_amdgcn_sched_barrier(0);
#pragma unroll
    for (int i = 0; i < 4; ++i) {
      int r = i * 4 + wv;
      *(bf16x8*)(hst + r * 512 + ((lane ^ (r & 7)) << 3)) = tlo[i];
    }
    __syncthreads();
#pragma unroll
    for (int kk = 0; kk < 16; ++kk) {  // A-lo x B-hi
      int c = kk * 4 + (lane >> 4), r = lane & 15;
      bf16x8 al = *(const bf16x8*)(hst + r * 512 + ((c ^ (r & 7)) << 3));
      bf16x8 bv;
      if constexpr (LWH) {
        int k16 = 4 * kk + (lane >> 4);
        bv = *(const bf16x8*)(wlds + lc * K1 + ((k16 ^ (lc & 7)) << 3));
      } else {
        bv = *(const bf16x8*)(Wht + (size_t)gcl * K1 + kk * 32 + (lane >> 4) * 8);
      }
      if (kk & 1)
        acc1 = __builtin_amdgcn_mfma_f32_16x16x32_bf16(al, bv, acc1, 0, 0, 0);
      else
        acc0 = __builtin_amdgcn_mfma_f32_16x16x32_bf16(al, bv, acc0, 0, 0, 0);
    }
    f32x4 a = acc0 + acc1;
    for (int r = 0; r < 4; ++r)
      glds[wv][((lane >> 4) << 2) + r][lane & 15] = a[r];
    __syncthreads();
    float hv;
    {
      float gi = glds[0][row][col] + x0;
      float gf = glds[1][row][col] + x1;
      float go = glds[2][row][col] + x2;
      float gg = glds[3][row][col] + x3;
      float si = sigf(gi), sf = sigf(gf), so = sigf(go);
      float tg2 = tanhft(gg);
      float cn = sf * creg + si * tg2;
      creg = cn;
      hv = so * tanhft(cn);
      unsigned short hi2 = f2bf(hv);
      unsigned short lo2 = f2bf(hv - bf2f(hi2));
      unsigned ohi = (unsigned)__shfl_xor((int)(unsigned)hi2, 1);
      unsigned olo = (unsigned)__shfl_xor((int)(unsigned)lo2, 1);
      if (col & 1)
        st4cc(hn + (size_t)n * K1 + 512 + (jh - 1), olo | ((unsigned)lo2 << 16));
      else
        st4cc(hn + (size_t)n * K1 + jh, (unsigned)hi2 | (ohi << 16));
    }
    // h committed to LLC, then publish; everything else AFTER the flag
    asm volatile("s_waitcnt vmcnt(0)" ::: "memory");
    __syncthreads();
    if (tid == 0) stflag(myflag, fl + 1);
    out[((size_t)n * T_ + tg) * H_ + jh] = hv;  // plain cached store
    if (tl + 1 < Tc) {  // prefetch next step's gate inputs (off crit path)
      const float* xr = xw + ((size_t)(tl + 1) * 64 + n) * FH + jh;
      x0 = xr[0]; x1 = xr[512]; x2 = xr[1024]; x3 = xr[1536];
    }
    ++fl;
  }
}

template <bool LWH>
__global__ void __launch_bounds__(BLK, 1)
lstm_persistent(const float* __restrict__ x, const float* __restrict__ h0,
                const float* __restrict__ Wx, const float* __restrict__ Wh,
                const float* __restrict__ b, float* __restrict__ out,
                void* __restrict__ ws, int Tc) {
  __shared__ __align__(16) short wlds[LWH ? 64 * K1 : 8];  // 128 KiB Wh slice
  __shared__ __align__(16) short sbuf[8192];  // 16 KiB: phase1 A/B | h stage
  __shared__ float glds[4][16][16];           // 4 KiB gate exchange

  char* wsb = (char*)ws;
  unsigned* relF   = (unsigned*)(wsb + 0);
  unsigned* chrdy  = (unsigned*)(wsb + 64);   // helper->stepper chunk flag
  unsigned* arrF   = (unsigned*)(wsb + 256);  // [256]
  unsigned* relJ   = (unsigned*)(wsb + 1280);
  unsigned* arrJ   = (unsigned*)(wsb + 1344); // [128]
  unsigned* arrH   = (unsigned*)(wsb + 2048); // [4][64] step flags
  short* Wxt   = (short*)(wsb + 4096);        // [2048][1024] bf16 hi|lo, W^T
  short* Wht   = Wxt + (size_t)FH * K1;
  short* hbuf0 = Wht + (size_t)FH * K1;       // [64][1024]
  short* hbuf1 = hbuf0 + N_ * K1;
  float* cbuf  = (float*)(hbuf1 + N_ * K1);   // [64][512] (unused; layout keep)
  short* xprim = (short*)(cbuf + N_ * H_);    // [Tc*64][1024]
  float* xwxb  = (float*)(xprim + (size_t)Tc * N_ * K1);  // 2 x [Tc*64][2048]

  const int tid = threadIdx.x;
  const int wg = blockIdx.x;
  const int gtid = wg * BLK + tid;
  const bool isStep = wg < NSTEP;
  const int rb = wg >> 5, cg = wg & 31;  // steppers
  const int hid = wg - NSTEP;            // helpers

  unsigned genF = 0, genJ = 0, fl = 0;

  // ---- prep: split-transpose weights (octet-wise), h0 ----
  for (int idx = gtid; idx < 2 * FH * 64; idx += NWG * BLK) {
    int m = idx >> 17;
    int rr = idx & 131071;
    int j = rr >> 6;
    int oct = rr & 63;
    const float* W = m ? Wh : Wx;
    bf16x8 hv, lv;
#pragma unroll
    for (int i = 0; i < 8; ++i) {
      float v = W[(size_t)(oct * 8 + i) * FH + j];
      unsigned short h = f2bf(v);
      hv[i] = (short)h;
      lv[i] = (short)f2bf(v - bf2f(h));
    }
    short* dst = m ? Wht : Wxt;
    *(bf16x8*)(dst + (size_t)j * K1 + oct * 8) = hv;
    *(bf16x8*)(dst + (size_t)j * K1 + 512 + oct * 8) = lv;
  }
  for (int idx = gtid; idx < N_ * H_; idx += NWG * BLK) {
    int n = idx >> 9, k = idx & 511;
    float v = h0[idx];
    unsigned short hi = f2bf(v);
    unsigned short lo = f2bf(v - bf2f(hi));
    hbuf0[n * K1 + k] = (short)hi;
    hbuf0[n * K1 + 512 + k] = (short)lo;
  }
  gbar2<4>(arrF, relF, ++genF, wg);

  // ---- steppers: Wh slice -> LDS (XOR-swizzled 16B units) ----
  if constexpr (LWH) {
    if (isStep) {
      for (int u = tid; u < 64 * 128; u += BLK) {
        int lc = u >> 7, k16 = u & 127;
        int gc = ((lc >> 4) << 9) + cg * 16 + (lc & 15);
        int4 v = *(const int4*)(Wht + (size_t)gc * K1 + k16 * 8);
        *(int4*)(wlds + lc * K1 + ((k16 ^ (lc & 7)) << 3)) = v;
      }
    }
    __syncthreads();
  }

  const int nCh = T_ / Tc;
  const int Mch = Tc * N_;
  const int nTiles = (Mch >> 7) * (FH >> 7);
  const size_t xwStride = (size_t)Mch * FH;

  // ---- chunk 0 front work (all WGs) ----
  convert_x(x, xprim, 0, Mch, gtid, NWG * BLK);
  gbar2<2>(arrF, relF, ++genF, wg);
  phase1(xprim, Wxt, b, xwxb, nTiles, wg, NWG, sbuf, sbuf + 4096);
  gbar2<2>(arrF, relF, ++genF, wg);

  if (isStep) {
    // ---- steppers: flag-gated chunks, no grid barrier in steady state ----
    float creg = 0.0f;
    for (int ch = 0; ch < nCh; ++ch) {
      if (ch > 0) {
        if (tid == 0) {
          int guard = 0;
          while (ldflag(chrdy) < (unsigned)ch) {
            __builtin_amdgcn_s_sleep(8);
            if (++guard > (1 << 20)) break;
          }
          __builtin_amdgcn_fence(__ATOMIC_ACQUIRE, "agent");  // drop stale xw
        }
        __syncthreads();
      }
      run_steps<LWH>(rb, cg, ch * Tc, Tc, fl, creg, wlds, Wht, hbuf0, hbuf1,
                     xwxb + (size_t)(ch & 1) * xwStride, out, arrH, sbuf, glds);
    }
  } else {
    // ---- helpers: produce xwxb for chunk ch+1 while steppers run ch ----
    for (int ch = 0; ch + 1 < nCh; ++ch) {
      if (ch > 0) {
        // steppers must be done reading buffer (ch+1)&1 (their chunk ch-1)
        if (tid < 64) {
          unsigned need = (unsigned)(ch * Tc);
          int guard = 0;
          for (;;) {
            unsigned v0 = ldflag(&arrH[(tid >> 5) * 64 + (tid & 31)]);
            unsigned v1 = ldflag(&arrH[128 + (tid >> 5) * 64 + (tid & 31)]);
            if (__all(v0 >= need && v1 >= need)) break;
            __builtin_amdgcn_s_sleep(8);
            if (++guard > (1 << 20)) break;
          }
        }
        __syncthreads();
      }
      convert_x(x, xprim, (ch + 1) * Tc, Mch, hid * BLK + tid, NHELP * BLK);
      hbar<1>(arrJ, relJ, ++genJ, hid);
      phase1(xprim, Wxt, b, xwxb + (size_t)((ch + 1) & 1) * xwStride, nTiles,
             hid, NHELP, sbuf, sbuf + 4096);
      hbar<1>(arrJ, relJ, ++genJ, hid);  // entry fence flushes phase1 writes
      if (hid == 0 && tid == 0) stflag(chrdy, (unsigned)(ch + 1));
    }
  }
}

extern "C" void kernel_launch(void* const* d_in, const int* in_sizes, int n_in,
                              void* d_out, int out_size, void* d_ws, size_t ws_size,
                              hipStream_t stream) {
  (void)in_sizes; (void)n_in; (void)out_size;
  const float* x  = (const float*)d_in[0];
  const float* h0 = (const float*)d_in[1];
  const float* Wx = (const float*)d_in[2];
  const float* Wh = (const float*)d_in[3];
  const float* b  = (const float*)d_in[4];
  float* out = (float*)d_out;

  size_t fixed = 4096 + 2 * (size_t)FH * K1 * 2 + 2 * (size_t)N_ * K1 * 2 +
                 (size_t)N_ * H_ * 4;
  size_t perTc = (size_t)N_ * K1 * 2 + 2 * (size_t)N_ * FH * 4;
  int Tc = 64;
  while (Tc > 1 && fixed + (size_t)Tc * perTc > ws_size) Tc >>= 1;

  (void)hipMemsetAsync(d_ws, 0, 4096, stream);  // reset barriers every replay

  void* args[] = {(void*)&x, (void*)&h0, (void*)&Wx, (void*)&Wh,
                  (void*)&b, (void*)&out, (void*)&d_ws, (void*)&Tc};

  // Path A: cooperative launch (static 148 KiB LDS -> 1 WG/CU, 256 WGs fit).
  hipError_t e = hipLaunchCooperativeKernel((void*)lstm_persistent<true>,
                                            dim3(NWG), dim3(BLK), args, 0,
                                            stream);
  if (e != hipSuccess) {
    // Path B: plain launch (custom barriers only need co-residency).
    (void)hipGetLastError();
    lstm_persistent<true><<<dim3(NWG), dim3(BLK), 0, stream>>>(
        x, h0, Wx, Wh, b, out, d_ws, Tc);
    e = hipGetLastError();
  }
  if (e != hipSuccess) {
    // Path C: fallback — Wh read from global, tiny LDS.
    (void)hipGetLastError();
    lstm_persistent<false><<<dim3(NWG), dim3(BLK), 0, stream>>>(
        x, h0, Wx, Wh, b, out, d_ws, Tc);
    (void)hipGetLastError();
  }
}

// Round 9
// 2381.849 us; speedup vs baseline: 1.0290x; 1.0290x over previous
//
#include <hip/hip_runtime.h>
#include <hip/hip_bf16.h>

#define N_  64
#define T_  512
#define D_  512
#define H_  512
#define FH  2048   // 4H
#define K1  1024   // hi|lo packed columns
#define NWG 256
#define NSTEP 128
#define NHELP 128
#define BLK 256

typedef __attribute__((ext_vector_type(4))) float f32x4;
typedef __attribute__((ext_vector_type(8))) short bf16x8;

__device__ __forceinline__ unsigned short f2bf(float f) {
  unsigned u = __float_as_uint(f);
  return (unsigned short)((u + 0x7FFFu + ((u >> 16) & 1u)) >> 16);
}
__device__ __forceinline__ float bf2f(unsigned short s) {
  return __uint_as_float(((unsigned)s) << 16);
}
__device__ __forceinline__ float sigf(float x) {
  return 1.0f / (1.0f + __expf(-x));
}
__device__ __forceinline__ float tanhft(float x) {  // branch-free tanh
  x = fminf(15.f, fmaxf(-15.f, x));
  float e = __expf(2.f * x);
  return (e - 1.f) / (e + 1.f);
}

__device__ __forceinline__ void gl_lds16(const void* g, void* l) {
  __builtin_amdgcn_global_load_lds(
      (const __attribute__((address_space(1))) void*)g,
      (__attribute__((address_space(3))) void*)l, 16, 0, 0);
}

// --- GLOBAL (LLC, sc0 sc1) ops: proven cross-XCD path (R5-R8) ---
// --- LOCAL (XCD L2) ops: plain store (writeback L2) + sc0 load (L1 bypass) ---
template <bool L2O>  // L2O=true -> XCD-local
__device__ __forceinline__ bf16x8 ld16h(const short* p) {
  bf16x8 d;
  if constexpr (L2O)
    asm volatile("global_load_dwordx4 %0, %1, off sc0" : "=v"(d) : "v"(p));
  else
    asm volatile("global_load_dwordx4 %0, %1, off sc0 sc1" : "=v"(d) : "v"(p));
  return d;
}
template <bool L2O>
__device__ __forceinline__ void st4h(short* p, unsigned v) {
  if constexpr (L2O)
    asm volatile("global_store_dword %0, %1, off" ::"v"(p), "v"(v) : "memory");
  else
    asm volatile("global_store_dword %0, %1, off sc0 sc1" ::"v"(p), "v"(v)
                 : "memory");
}
template <bool L2O>
__device__ __forceinline__ unsigned ldflagT(const unsigned* p) {
  unsigned v;  // embedded waitcnt: value valid on return (rule-18 safe)
  if constexpr (L2O)
    asm volatile("global_load_dword %0, %1, off sc0\ns_waitcnt vmcnt(0)"
                 : "=v"(v) : "v"(p) : "memory");
  else
    asm volatile("global_load_dword %0, %1, off sc0 sc1\ns_waitcnt vmcnt(0)"
                 : "=v"(v) : "v"(p) : "memory");
  return v;
}
template <bool L2O>
__device__ __forceinline__ void stflagT(unsigned* p, unsigned v) {
  if constexpr (L2O)
    asm volatile("global_store_dword %0, %1, off" ::"v"(p), "v"(v) : "memory");
  else
    asm volatile("global_store_dword %0, %1, off sc0 sc1" ::"v"(p), "v"(v)
                 : "memory");
}
__device__ __forceinline__ unsigned ldflag(const unsigned* p) {
  return ldflagT<false>(p);
}
__device__ __forceinline__ void stflag(unsigned* p, unsigned v) {
  stflagT<false>(p, v);
}
// LLC-coherent float load, compiler-tracked waitcnt (for xw gate inputs).
__device__ __forceinline__ float ldf_cc(const float* p) {
  return __hip_atomic_load(p, __ATOMIC_RELAXED, __HIP_MEMORY_SCOPE_AGENT);
}

// Grid barrier over 256 WGs (prologue only).
template <int SLP>
__device__ __forceinline__ void gbar2(unsigned* arr, unsigned* rel,
                                      unsigned gen, int wg) {
  __syncthreads();
  const int tid = threadIdx.x;
  if (tid == 0) {
    __builtin_amdgcn_fence(__ATOMIC_RELEASE, "agent");
    __hip_atomic_store(&arr[wg], gen, __ATOMIC_RELAXED,
                       __HIP_MEMORY_SCOPE_AGENT);
  }
  if (wg == 0) {
    if (tid < 64) {
      int guard = 0;
      for (;;) {
        unsigned v0 = __hip_atomic_load(&arr[tid], __ATOMIC_RELAXED,
                                        __HIP_MEMORY_SCOPE_AGENT);
        unsigned v1 = __hip_atomic_load(&arr[tid + 64], __ATOMIC_RELAXED,
                                        __HIP_MEMORY_SCOPE_AGENT);
        unsigned v2 = __hip_atomic_load(&arr[tid + 128], __ATOMIC_RELAXED,
                                        __HIP_MEMORY_SCOPE_AGENT);
        unsigned v3 = __hip_atomic_load(&arr[tid + 192], __ATOMIC_RELAXED,
                                        __HIP_MEMORY_SCOPE_AGENT);
        if (__all(v0 >= gen && v1 >= gen && v2 >= gen && v3 >= gen)) break;
        __builtin_amdgcn_s_sleep(SLP);
        if (++guard > (1 << 20)) break;
      }
    }
    __syncthreads();
    if (tid == 0)
      __hip_atomic_store(rel, gen, __ATOMIC_RELAXED, __HIP_MEMORY_SCOPE_AGENT);
  } else if (tid == 0) {
    int guard = 0;
    while (__hip_atomic_load(rel, __ATOMIC_RELAXED,
                             __HIP_MEMORY_SCOPE_AGENT) < gen) {
      __builtin_amdgcn_s_sleep(SLP);
      if (++guard > (1 << 20)) break;
    }
  }
  if (tid == 0) __builtin_amdgcn_fence(__ATOMIC_ACQUIRE, "agent");
  __syncthreads();
}

// Helper-group barrier (128 helper WGs); poller hid==0.
template <int SLP>
__device__ __forceinline__ void hbar(unsigned* arr, unsigned* rel,
                                     unsigned gen, int hid) {
  __syncthreads();
  const int tid = threadIdx.x;
  if (tid == 0) {
    __builtin_amdgcn_fence(__ATOMIC_RELEASE, "agent");
    __hip_atomic_store(&arr[hid], gen, __ATOMIC_RELAXED,
                       __HIP_MEMORY_SCOPE_AGENT);
  }
  if (hid == 0) {
    if (tid < 64) {
      int guard = 0;
      for (;;) {
        unsigned v0 = __hip_atomic_load(&arr[tid], __ATOMIC_RELAXED,
                                        __HIP_MEMORY_SCOPE_AGENT);
        unsigned v1 = __hip_atomic_load(&arr[tid + 64], __ATOMIC_RELAXED,
                                        __HIP_MEMORY_SCOPE_AGENT);
        if (__all(v0 >= gen && v1 >= gen)) break;
        __builtin_amdgcn_s_sleep(SLP);
        if (++guard > (1 << 20)) break;
      }
    }
    __syncthreads();
    if (tid == 0)
      __hip_atomic_store(rel, gen, __ATOMIC_RELAXED, __HIP_MEMORY_SCOPE_AGENT);
  } else if (tid == 0) {
    int guard = 0;
    while (__hip_atomic_load(rel, __ATOMIC_RELAXED,
                             __HIP_MEMORY_SCOPE_AGENT) < gen) {
      __builtin_amdgcn_s_sleep(SLP);
      if (++guard > (1 << 20)) break;
    }
  }
  if (tid == 0) __builtin_amdgcn_fence(__ATOMIC_ACQUIRE, "agent");
  __syncthreads();
}

// x chunk -> hi/lo bf16 (octet-wise coalesced)
__device__ __forceinline__ void convert_x(const float* __restrict__ x,
                                          short* __restrict__ xprim, int t0,
                                          int Mch, int idx0, int stride) {
  for (int idx = idx0; idx < Mch * 64; idx += stride) {
    int mrow = idx >> 6, oct = idx & 63;
    int tl = mrow >> 6, n = mrow & 63;
    const float* src = x + ((size_t)n * T_ + (t0 + tl)) * D_ + oct * 8;
    bf16x8 hv, lv;
#pragma unroll
    for (int i = 0; i < 8; ++i) {
      float v = src[i];
      unsigned short h = f2bf(v);
      hv[i] = (short)h;
      lv[i] = (short)f2bf(v - bf2f(h));
    }
    *(bf16x8*)(xprim + (size_t)mrow * K1 + oct * 8) = hv;
    *(bf16x8*)(xprim + (size_t)mrow * K1 + 512 + oct * 8) = lv;
  }
}

// Phase-1 GEMM: xw = x' @ Wx' + b (128x128 tiles, K'=1536, split-bf16)
__device__ __forceinline__ void phase1(const short* __restrict__ xprim,
                                       const short* __restrict__ Wxt,
                                       const float* __restrict__ b,
                                       float* __restrict__ xw, int nTiles,
                                       int tile0, int tstride, short* Asm,
                                       short* Bsm) {
  const int tid = threadIdx.x;
  const int lane = tid & 63, wv = tid >> 6;
  const int wm = wv >> 1, wn = wv & 1;
  const int sslot = (lane & 3) ^ ((lane >> 3) & 3);
  for (int tile = tile0; tile < nTiles; tile += tstride) {
    int tm = tile >> 4, tn = tile & 15;
    int m0 = tm << 7, n0 = tn << 7;
    f32x4 acc[4][4];
    for (int i = 0; i < 4; ++i)
      for (int j = 0; j < 4; ++j) acc[i][j] = (f32x4){0.f, 0.f, 0.f, 0.f};
    for (int kk = 0; kk < 48; ++kk) {
      int ac = (kk < 16 ? kk : kk - 16) << 5;
      int bc = (kk < 32 ? kk : kk - 32) << 5;
      __syncthreads();
      {
        const short* sa =
            xprim + (size_t)(m0 + wv * 32 + (lane >> 2)) * K1 + ac + sslot * 8;
        gl_lds16(sa, Asm + (wv * 32) * 32);
        gl_lds16(sa + (size_t)16 * K1, Asm + (wv * 32 + 16) * 32);
        const short* sb =
            Wxt + (size_t)(n0 + wv * 32 + (lane >> 2)) * K1 + bc + sslot * 8;
        gl_lds16(sb, Bsm + (wv * 32) * 32);
        gl_lds16(sb + (size_t)16 * K1, Bsm + (wv * 32 + 16) * 32);
      }
      __syncthreads();
      bf16x8 af[4], bfr[4];
      for (int mi = 0; mi < 4; ++mi) {
        int R = wm * 64 + mi * 16 + (lane & 15);
        int rs = ((lane >> 4) & 3) ^ ((R >> 1) & 3);
        af[mi] = *(const bf16x8*)(Asm + R * 32 + rs * 8);
      }
      for (int ni = 0; ni < 4; ++ni) {
        int R = wn * 64 + ni * 16 + (lane & 15);
        int rs = ((lane >> 4) & 3) ^ ((R >> 1) & 3);
        bfr[ni] = *(const bf16x8*)(Bsm + R * 32 + rs * 8);
      }
      for (int mi = 0; mi < 4; ++mi)
        for (int ni = 0; ni < 4; ++ni)
          acc[mi][ni] = __builtin_amdgcn_mfma_f32_16x16x32_bf16(
              af[mi], bfr[ni], acc[mi][ni], 0, 0, 0);
    }
    for (int ni = 0; ni < 4; ++ni) {
      float bj = b[n0 + wn * 64 + ni * 16 + (lane & 15)];
      for (int mi = 0; mi < 4; ++mi) {
        int mg = m0 + wm * 64 + mi * 16 + ((lane >> 4) << 2);
        float* dst = xw + (size_t)mg * FH + n0 + wn * 64 + ni * 16 + (lane & 15);
        for (int r = 0; r < 4; ++r) dst[(size_t)r * FH] = acc[mi][ni][r] + bj;
      }
    }
  }
}

// Recurrent steps. L2O=true: all h/flag traffic stays in the group's XCD L2.
template <bool LWH, bool L2O>
__device__ __forceinline__ void run_steps(
    int rb, int cg, int t0, int Tc, unsigned& fl, float& creg,
    const short* wlds, const short* __restrict__ Wht, short* hbuf0,
    short* hbuf1, const float* __restrict__ xw, float* __restrict__ out,
    unsigned* arrH, unsigned* cdone, int chIdx, short* hst,
    float (*glds)[16][16]) {
  const int tid = threadIdx.x;
  const int lane = tid & 63, wv = tid >> 6;
  const int lc = wv * 16 + (lane & 15);
  const int gcl = wv * 512 + cg * 16 + (lane & 15);
  const int row = tid >> 4, col = tid & 15;
  const int n = rb * 16 + row, jh = cg * 16 + col;
  unsigned* myflag = &arrH[rb * 32 + cg];
  unsigned* grp = &arrH[rb * 32];

  // gate inputs for step 0 (LLC-coherent, compiler-tracked waits)
  const float* xr0 = xw + ((size_t)n) * FH + jh;
  float x0 = ldf_cc(xr0), x1 = ldf_cc(xr0 + 512), x2 = ldf_cc(xr0 + 1024),
        x3 = ldf_cc(xr0 + 1536);

  for (int tl = 0; tl < Tc; ++tl) {
    const int tg = t0 + tl;
    if (wv == 0) {
      int guard = 0;
      for (;;) {
        unsigned v = ldflagT<L2O>(grp + (lane & 31));
        if (__all(v >= fl)) break;
        __builtin_amdgcn_s_sleep(L2O ? 0 : 1);
        if (++guard > (1 << 20)) break;
      }
    }
    __syncthreads();
    // group advanced past chunk boundary -> tell helpers (always LLC)
    if (tl == 0 && cg == 0 && tid == 0) stflag(cdone, (unsigned)chIdx);

    const short* hc = (tg & 1) ? hbuf1 : hbuf0;
    short* hn = (tg & 1) ? hbuf0 : hbuf1;

    // stage hi-half: row r=i*4+wv (uniform/instr), octet=lane -> LDS slots
    // lane^(r&7): bijection over 0..63 -> conflict-free writes.
    bf16x8 tmp[4];
#pragma unroll
    for (int i = 0; i < 4; ++i) {
      int r = i * 4 + wv;
      tmp[i] = ld16h<L2O>(hc + (size_t)(rb * 16 + r) * K1 + lane * 8);
    }
    asm volatile("s_waitcnt vmcnt(0)" ::: "memory");
    __builtin_amdgcn_sched_barrier(0);
#pragma unroll
    for (int i = 0; i < 4; ++i) {
      int r = i * 4 + wv;
      *(bf16x8*)(hst + r * 512 + ((lane ^ (r & 7)) << 3)) = tmp[i];
    }
    __syncthreads();
    bf16x8 af[16];
#pragma unroll
    for (int kk = 0; kk < 16; ++kk) {
      int c = kk * 4 + (lane >> 4), r = lane & 15;
      af[kk] = *(const bf16x8*)(hst + r * 512 + ((c ^ (r & 7)) << 3));
    }
    __syncthreads();  // hst free for lo

    bf16x8 tlo[4];  // lo-half loads hide under the 32 hi MFMAs
#pragma unroll
    for (int i = 0; i < 4; ++i) {
      int r = i * 4 + wv;
      tlo[i] = ld16h<L2O>(hc + (size_t)(rb * 16 + r) * K1 + 512 + lane * 8);
    }
    f32x4 acc0 = {0.f, 0.f, 0.f, 0.f};
    f32x4 acc1 = {0.f, 0.f, 0.f, 0.f};
#pragma unroll
    for (int kk = 0; kk < 32; ++kk) {  // A-hi x (B-hi | B-lo)
      bf16x8 bv;
      if constexpr (LWH) {
        int k16 = 4 * kk + (lane >> 4);
        bv = *(const bf16x8*)(wlds + lc * K1 + ((k16 ^ (lc & 7)) << 3));
      } else {
        bv = *(const bf16x8*)(Wht + (size_t)gcl * K1 + kk * 32 + (lane >> 4) * 8);
      }
      if (kk & 1)
        acc1 = __builtin_amdgcn_mfma_f32_16x16x32_bf16(af[kk & 15], bv, acc1,
                                                       0, 0, 0);
      else
        acc0 = __builtin_amdgcn_mfma_f32_16x16x32_bf16(af[kk & 15], bv, acc0,
                                                       0, 0, 0);
    }
    asm volatile("s_waitcnt vmcnt(0)" ::: "memory");
    __builtin_amdgcn_sched_barrier(0);
#pragma unroll
    for (int i = 0; i < 4; ++i) {
      int r = i * 4 + wv;
      *(bf16x8*)(hst + r * 512 + ((lane ^ (r & 7)) << 3)) = tlo[i];
    }
    __syncthreads();
#pragma unroll
    for (int kk = 0; kk < 16; ++kk) {  // A-lo x B-hi
      int c = kk * 4 + (lane >> 4), r = lane & 15;
      bf16x8 al = *(const bf16x8*)(hst + r * 512 + ((c ^ (r & 7)) << 3));
      bf16x8 bv;
      if constexpr (LWH) {
        int k16 = 4 * kk + (lane >> 4);
        bv = *(const bf16x8*)(wlds + lc * K1 + ((k16 ^ (lc & 7)) << 3));
      } else {
        bv = *(const bf16x8*)(Wht + (size_t)gcl * K1 + kk * 32 + (lane >> 4) * 8);
      }
      if (kk & 1)
        acc1 = __builtin_amdgcn_mfma_f32_16x16x32_bf16(al, bv, acc1, 0, 0, 0);
      else
        acc0 = __builtin_amdgcn_mfma_f32_16x16x32_bf16(al, bv, acc0, 0, 0, 0);
    }
    f32x4 a = acc0 + acc1;
    for (int r = 0; r < 4; ++r)
      glds[wv][((lane >> 4) << 2) + r][lane & 15] = a[r];
    __syncthreads();
    float hv;
    {
      float gi = glds[0][row][col] + x0;
      float gf = glds[1][row][col] + x1;
      float go = glds[2][row][col] + x2;
      float gg = glds[3][row][col] + x3;
      float si = sigf(gi), sf = sigf(gf), so = sigf(go);
      float tg2 = tanhft(gg);
      float cn = sf * creg + si * tg2;
      creg = cn;
      hv = so * tanhft(cn);
      unsigned short hi2 = f2bf(hv);
      unsigned short lo2 = f2bf(hv - bf2f(hi2));
      unsigned ohi = (unsigned)__shfl_xor((int)(unsigned)hi2, 1);
      unsigned olo = (unsigned)__shfl_xor((int)(unsigned)lo2, 1);
      if (col & 1)
        st4h<L2O>(hn + (size_t)n * K1 + 512 + (jh - 1),
                  olo | ((unsigned)lo2 << 16));
      else
        st4h<L2O>(hn + (size_t)n * K1 + jh, (unsigned)hi2 | (ohi << 16));
    }
    asm volatile("s_waitcnt vmcnt(0)" ::: "memory");  // h committed
    __syncthreads();
    if (tid == 0) stflagT<L2O>(myflag, fl + 1);
    out[((size_t)n * T_ + tg) * H_ + jh] = hv;  // plain cached store
    if (tl + 1 < Tc) {  // prefetch next gate inputs (off crit path)
      const float* xr = xw + ((size_t)(tl + 1) * 64 + n) * FH + jh;
      x0 = ldf_cc(xr); x1 = ldf_cc(xr + 512);
      x2 = ldf_cc(xr + 1024); x3 = ldf_cc(xr + 1536);
    }
    ++fl;
  }
}

template <bool LWH>
__global__ void __launch_bounds__(BLK, 1)
lstm_persistent(const float* __restrict__ x, const float* __restrict__ h0,
                const float* __restrict__ Wx, const float* __restrict__ Wh,
                const float* __restrict__ b, float* __restrict__ out,
                void* __restrict__ ws, int Tc) {
  __shared__ __align__(16) short wlds[LWH ? 64 * K1 : 8];  // 128 KiB Wh slice
  __shared__ __align__(16) short sbuf[8192];  // 16 KiB: phase1 A/B | h stage
  __shared__ float glds[4][16][16];           // 4 KiB gate exchange
  __shared__ int okshare;

  char* wsb = (char*)ws;
  unsigned* relF   = (unsigned*)(wsb + 0);
  unsigned* chrdy  = (unsigned*)(wsb + 64);   // helper->stepper chunk flag
  unsigned* cdone  = (unsigned*)(wsb + 128);  // [4] stepper->helper progress
  unsigned* arrF   = (unsigned*)(wsb + 256);  // [256]
  unsigned* relJ   = (unsigned*)(wsb + 1280);
  unsigned* arrJ   = (unsigned*)(wsb + 1344); // [128]
  unsigned* arrH   = (unsigned*)(wsb + 2048); // [4][32] step flags
  unsigned* tok    = (unsigned*)(wsb + 2560); // [4][32] handshake tokens
  unsigned* okarr  = (unsigned*)(wsb + 3072); // [4][32] handshake verdicts
  short* Wxt   = (short*)(wsb + 4096);        // [2048][1024] bf16 hi|lo, W^T
  short* Wht   = Wxt + (size_t)FH * K1;
  short* hbuf0 = Wht + (size_t)FH * K1;       // [64][1024]
  short* hbuf1 = hbuf0 + N_ * K1;
  float* cbuf  = (float*)(hbuf1 + N_ * K1);   // (layout keep)
  short* xprim = (short*)(cbuf + N_ * H_);    // [Tc*64][1024]
  float* xwxb  = (float*)(xprim + (size_t)Tc * N_ * K1);  // 2 x [Tc*64][2048]

  const int tid = threadIdx.x;
  const int wg = blockIdx.x;
  const int gtid = wg * BLK + tid;
  const int lane = tid & 63, wv = tid >> 6;
  // XCD-aligned roles under round-robin dispatch (wg%8 -> XCD):
  const bool isStep = (wg & 7) < 4;
  const int rb = wg & 7;                       // group = one XCD (0..3)
  const int cg = wg >> 3;                      // 0..31 within group
  const int hid = (wg >> 3) * 4 + ((wg & 7) - 4);  // 0..127 for helpers

  unsigned genF = 0, genJ = 0, fl = 0;

  // ---- prep: split-transpose weights (octet-wise), h0 ----
  for (int idx = gtid; idx < 2 * FH * 64; idx += NWG * BLK) {
    int m = idx >> 17;
    int rr = idx & 131071;
    int j = rr >> 6;
    int oct = rr & 63;
    const float* W = m ? Wh : Wx;
    bf16x8 hv, lv;
#pragma unroll
    for (int i = 0; i < 8; ++i) {
      float v = W[(size_t)(oct * 8 + i) * FH + j];
      unsigned short h = f2bf(v);
      hv[i] = (short)h;
      lv[i] = (short)f2bf(v - bf2f(h));
    }
    short* dst = m ? Wht : Wxt;
    *(bf16x8*)(dst + (size_t)j * K1 + oct * 8) = hv;
    *(bf16x8*)(dst + (size_t)j * K1 + 512 + oct * 8) = lv;
  }
  for (int idx = gtid; idx < N_ * H_; idx += NWG * BLK) {
    int n = idx >> 9, k = idx & 511;
    float v = h0[idx];
    unsigned short hi = f2bf(v);
    unsigned short lo = f2bf(v - bf2f(hi));
    hbuf0[n * K1 + k] = (short)hi;
    hbuf0[n * K1 + 512 + k] = (short)lo;
  }
  gbar2<4>(arrF, relF, ++genF, wg);

  // ---- steppers: Wh slice -> LDS; then XCD-locality handshake ----
  bool localok = false;
  if (isStep) {
    if constexpr (LWH) {
      for (int u = tid; u < 64 * 128; u += BLK) {
        int lc = u >> 7, k16 = u & 127;
        int gc = ((lc >> 4) << 9) + cg * 16 + (lc & 15);
        int4 v = *(const int4*)(Wht + (size_t)gc * K1 + k16 * 8);
        *(int4*)(wlds + lc * K1 + ((k16 ^ (lc & 7)) << 3)) = v;
      }
      __syncthreads();
    }
    // phase A: plain-store token; sc0-poll peers (bounded -> verdict)
    if (tid == 0) stflagT<true>(&tok[rb * 32 + cg], 1u);
    int ok = 0;
    if (wv == 0) {
      int guard = 0;
      for (;;) {
        unsigned v = ldflagT<true>(&tok[rb * 32 + (lane & 31)]);
        if (__all(v >= 1)) { ok = 1; break; }
        __builtin_amdgcn_s_sleep(2);
        if (++guard > 4096) break;
      }
    }
    if (tid == 0) okshare = ok;
    __syncthreads();
    ok = okshare;
    // phase B: exchange verdicts over the PROVEN sc0sc1 path; unanimity
    if (tid == 0) stflag(&okarr[rb * 32 + cg], 1u + (unsigned)ok);
    unsigned verdict = 1;
    if (wv == 0) {
      int guard = 0;
      for (;;) {
        unsigned v = ldflag(&okarr[rb * 32 + (lane & 31)]);
        if (__all(v >= 1)) { verdict = __all(v == 2) ? 2u : 1u; break; }
        __builtin_amdgcn_s_sleep(2);
        if (++guard > (1 << 20)) break;
      }
    }
    if (tid == 0) okshare = (int)verdict;
    __syncthreads();
    localok = (okshare == 2);
  }

  const int nCh = T_ / Tc;
  const int Mch = Tc * N_;
  const int nTiles = (Mch >> 7) * (FH >> 7);
  const size_t xwStride = (size_t)Mch * FH;

  // ---- chunk 0 front work (all WGs) ----
  convert_x(x, xprim, 0, Mch, gtid, NWG * BLK);
  gbar2<2>(arrF, relF, ++genF, wg);
  phase1(xprim, Wxt, b, xwxb, nTiles, wg, NWG, sbuf, sbuf + 4096);
  gbar2<2>(arrF, relF, ++genF, wg);

  if (isStep) {
    float creg = 0.0f;
    for (int ch = 0; ch < nCh; ++ch) {
      if (ch > 0) {
        if (tid == 0) {
          int guard = 0;
          while (ldflag(chrdy) < (unsigned)ch) {
            __builtin_amdgcn_s_sleep(8);
            if (++guard > (1 << 20)) break;
          }
        }
        __syncthreads();  // no fence: xw read via LLC-coherent loads
      }
      const float* xw = xwxb + (size_t)(ch & 1) * xwStride;
      if (localok)
        run_steps<LWH, true>(rb, cg, ch * Tc, Tc, fl, creg, wlds, Wht, hbuf0,
                             hbuf1, xw, out, arrH, &cdone[rb], ch, sbuf, glds);
      else
        run_steps<LWH, false>(rb, cg, ch * Tc, Tc, fl, creg, wlds, Wht, hbuf0,
                              hbuf1, xw, out, arrH, &cdone[rb], ch, sbuf, glds);
    }
  } else {
    // helpers: produce xwxb[ch+1] while steppers run ch; gate on cdone (LLC)
    for (int ch = 0; ch + 1 < nCh; ++ch) {
      if (ch > 0) {
        if (tid == 0) {
          int guard = 0;
          for (;;) {
            unsigned d0 = ldflag(&cdone[0]);
            unsigned d1 = ldflag(&cdone[1]);
            unsigned d2 = ldflag(&cdone[2]);
            unsigned d3 = ldflag(&cdone[3]);
            if (d0 >= (unsigned)ch && d1 >= (unsigned)ch &&
                d2 >= (unsigned)ch && d3 >= (unsigned)ch)
              break;
            __builtin_amdgcn_s_sleep(16);
            if (++guard > (1 << 20)) break;
          }
        }
        __syncthreads();
      }
      convert_x(x, xprim, (ch + 1) * Tc, Mch, hid * BLK + tid, NHELP * BLK);
      hbar<1>(arrJ, relJ, ++genJ, hid);
      phase1(xprim, Wxt, b, xwxb + (size_t)((ch + 1) & 1) * xwStride, nTiles,
             hid, NHELP, sbuf, sbuf + 4096);
      hbar<1>(arrJ, relJ, ++genJ, hid);  // release fences flush phase1 writes
      if (hid == 0 && tid == 0) stflag(chrdy, (unsigned)(ch + 1));
    }
  }
}

extern "C" void kernel_launch(void* const* d_in, const int* in_sizes, int n_in,
                              void* d_out, int out_size, void* d_ws, size_t ws_size,
                              hipStream_t stream) {
  (void)in_sizes; (void)n_in; (void)out_size;
  const float* x  = (const float*)d_in[0];
  const float* h0 = (const float*)d_in[1];
  const float* Wx = (const float*)d_in[2];
  const float* Wh = (const float*)d_in[3];
  const float* b  = (const float*)d_in[4];
  float* out = (float*)d_out;

  size_t fixed = 4096 + 2 * (size_t)FH * K1 * 2 + 2 * (size_t)N_ * K1 * 2 +
                 (size_t)N_ * H_ * 4;
  size_t perTc = (size_t)N_ * K1 * 2 + 2 * (size_t)N_ * FH * 4;
  int Tc = 64;
  while (Tc > 1 && fixed + (size_t)Tc * perTc > ws_size) Tc >>= 1;

  (void)hipMemsetAsync(d_ws, 0, 4096, stream);  // reset barriers every replay

  void* args[] = {(void*)&x, (void*)&h0, (void*)&Wx, (void*)&Wh,
                  (void*)&b, (void*)&out, (void*)&d_ws, (void*)&Tc};

  // Path A: cooperative launch (static 148 KiB LDS -> 1 WG/CU, 256 WGs fit).
  hipError_t e = hipLaunchCooperativeKernel((void*)lstm_persistent<true>,
                                            dim3(NWG), dim3(BLK), args, 0,
                                            stream);
  if (e != hipSuccess) {
    // Path B: plain launch (custom barriers only need co-residency).
    (void)hipGetLastError();
    lstm_persistent<true><<<dim3(NWG), dim3(BLK), 0, stream>>>(
        x, h0, Wx, Wh, b, out, d_ws, Tc);
    e = hipGetLastError();
  }
  if (e != hipSuccess) {
    // Path C: fallback — Wh read from global, tiny LDS.
    (void)hipGetLastError();
    lstm_persistent<false><<<dim3(NWG), dim3(BLK), 0, stream>>>(
        x, h0, Wx, Wh, b, out, d_ws, Tc);
    (void)hipGetLastError();
  }
}

// Round 12
// 1911.025 us; speedup vs baseline: 1.2825x; 1.2464x over previous
//
#include <hip/hip_runtime.h>
#include <hip/hip_bf16.h>

#define N_  64
#define T_  512
#define D_  512
#define H_  512
#define FH  2048   // 4H
#define K1  1024   // hi|lo packed columns
#define NWG 256
#define NSTEP 128
#define NHELP 128
#define BLK 256

typedef __attribute__((ext_vector_type(4))) float f32x4;
typedef __attribute__((ext_vector_type(8))) short bf16x8;

__device__ __forceinline__ unsigned short f2bf(float f) {
  unsigned u = __float_as_uint(f);
  return (unsigned short)((u + 0x7FFFu + ((u >> 16) & 1u)) >> 16);
}
__device__ __forceinline__ float bf2f(unsigned short s) {
  return __uint_as_float(((unsigned)s) << 16);
}
__device__ __forceinline__ float sigf(float x) {
  return 1.0f / (1.0f + __expf(-x));
}
__device__ __forceinline__ float tanhft(float x) {  // branch-free tanh
  x = fminf(15.f, fmaxf(-15.f, x));
  float e = __expf(2.f * x);
  return (e - 1.f) / (e + 1.f);
}

__device__ __forceinline__ void gl_lds16(const void* g, void* l) {
  __builtin_amdgcn_global_load_lds(
      (const __attribute__((address_space(1))) void*)g,
      (__attribute__((address_space(3))) void*)l, 16, 0, 0);
}

// LLC-coherent ops (sc0 sc1): the R5-R8-proven cross-XCD handoff path.
// LOCAL/XCD-L2 variants are permanently removed: a group with a MIXED
// local/global verdict wedges (dirty-L2 flag line never refetched) — the
// R6/R10/R11 failure class.
__device__ __forceinline__ bf16x8 ld16cc(const short* p) {
  bf16x8 d;
  asm volatile("global_load_dwordx4 %0, %1, off sc0 sc1" : "=v"(d) : "v"(p));
  return d;
}
__device__ __forceinline__ void st4cc(short* p, unsigned v) {
  asm volatile("global_store_dword %0, %1, off sc0 sc1" ::"v"(p), "v"(v)
               : "memory");
}
__device__ __forceinline__ unsigned ldflag(const unsigned* p) {
  unsigned v;  // embedded waitcnt: value valid on return (rule-18 safe)
  asm volatile("global_load_dword %0, %1, off sc0 sc1\ns_waitcnt vmcnt(0)"
               : "=v"(v) : "v"(p) : "memory");
  return v;
}
__device__ __forceinline__ void stflag(unsigned* p, unsigned v) {
  asm volatile("global_store_dword %0, %1, off sc0 sc1" ::"v"(p), "v"(v)
               : "memory");
}
// LLC-coherent float load, compiler-tracked waitcnt (xw gate inputs).
__device__ __forceinline__ float ldf_cc(const float* p) {
  return __hip_atomic_load(p, __ATOMIC_RELAXED, __HIP_MEMORY_SCOPE_AGENT);
}

// Grid barrier over 256 WGs (prologue only).
template <int SLP>
__device__ __forceinline__ void gbar2(unsigned* arr, unsigned* rel,
                                      unsigned gen, int wg) {
  __syncthreads();
  const int tid = threadIdx.x;
  if (tid == 0) {
    __builtin_amdgcn_fence(__ATOMIC_RELEASE, "agent");
    __hip_atomic_store(&arr[wg], gen, __ATOMIC_RELAXED,
                       __HIP_MEMORY_SCOPE_AGENT);
  }
  if (wg == 0) {
    if (tid < 64) {
      int guard = 0;
      for (;;) {
        unsigned v0 = __hip_atomic_load(&arr[tid], __ATOMIC_RELAXED,
                                        __HIP_MEMORY_SCOPE_AGENT);
        unsigned v1 = __hip_atomic_load(&arr[tid + 64], __ATOMIC_RELAXED,
                                        __HIP_MEMORY_SCOPE_AGENT);
        unsigned v2 = __hip_atomic_load(&arr[tid + 128], __ATOMIC_RELAXED,
                                        __HIP_MEMORY_SCOPE_AGENT);
        unsigned v3 = __hip_atomic_load(&arr[tid + 192], __ATOMIC_RELAXED,
                                        __HIP_MEMORY_SCOPE_AGENT);
        if (__all(v0 >= gen && v1 >= gen && v2 >= gen && v3 >= gen)) break;
        __builtin_amdgcn_s_sleep(SLP);
        if (++guard > (1 << 20)) break;
      }
    }
    __syncthreads();
    if (tid == 0)
      __hip_atomic_store(rel, gen, __ATOMIC_RELAXED, __HIP_MEMORY_SCOPE_AGENT);
  } else if (tid == 0) {
    int guard = 0;
    while (__hip_atomic_load(rel, __ATOMIC_RELAXED,
                             __HIP_MEMORY_SCOPE_AGENT) < gen) {
      __builtin_amdgcn_s_sleep(SLP);
      if (++guard > (1 << 20)) break;
    }
  }
  if (tid == 0) __builtin_amdgcn_fence(__ATOMIC_ACQUIRE, "agent");
  __syncthreads();
}

// Helper-group barrier (128 helper WGs); poller hid==0.
template <int SLP>
__device__ __forceinline__ void hbar(unsigned* arr, unsigned* rel,
                                     unsigned gen, int hid) {
  __syncthreads();
  const int tid = threadIdx.x;
  if (tid == 0) {
    __builtin_amdgcn_fence(__ATOMIC_RELEASE, "agent");
    __hip_atomic_store(&arr[hid], gen, __ATOMIC_RELAXED,
                       __HIP_MEMORY_SCOPE_AGENT);
  }
  if (hid == 0) {
    if (tid < 64) {
      int guard = 0;
      for (;;) {
        unsigned v0 = __hip_atomic_load(&arr[tid], __ATOMIC_RELAXED,
                                        __HIP_MEMORY_SCOPE_AGENT);
        unsigned v1 = __hip_atomic_load(&arr[tid + 64], __ATOMIC_RELAXED,
                                        __HIP_MEMORY_SCOPE_AGENT);
        if (__all(v0 >= gen && v1 >= gen)) break;
        __builtin_amdgcn_s_sleep(SLP);
        if (++guard > (1 << 20)) break;
      }
    }
    __syncthreads();
    if (tid == 0)
      __hip_atomic_store(rel, gen, __ATOMIC_RELAXED, __HIP_MEMORY_SCOPE_AGENT);
  } else if (tid == 0) {
    int guard = 0;
    while (__hip_atomic_load(rel, __ATOMIC_RELAXED,
                             __HIP_MEMORY_SCOPE_AGENT) < gen) {
      __builtin_amdgcn_s_sleep(SLP);
      if (++guard > (1 << 20)) break;
    }
  }
  if (tid == 0) __builtin_amdgcn_fence(__ATOMIC_ACQUIRE, "agent");
  __syncthreads();
}

// x chunk -> hi/lo bf16 (octet-wise coalesced)
__device__ __forceinline__ void convert_x(const float* __restrict__ x,
                                          short* __restrict__ xprim, int t0,
                                          int Mch, int idx0, int stride) {
  for (int idx = idx0; idx < Mch * 64; idx += stride) {
    int mrow = idx >> 6, oct = idx & 63;
    int tl = mrow >> 6, n = mrow & 63;
    const float* src = x + ((size_t)n * T_ + (t0 + tl)) * D_ + oct * 8;
    bf16x8 hv, lv;
#pragma unroll
    for (int i = 0; i < 8; ++i) {
      float v = src[i];
      unsigned short h = f2bf(v);
      hv[i] = (short)h;
      lv[i] = (short)f2bf(v - bf2f(h));
    }
    *(bf16x8*)(xprim + (size_t)mrow * K1 + oct * 8) = hv;
    *(bf16x8*)(xprim + (size_t)mrow * K1 + 512 + oct * 8) = lv;
  }
}

// Phase-1 GEMM: xw = x' @ Wx' + b (128x128 tiles, K'=1536, split-bf16)
__device__ __forceinline__ void phase1(const short* __restrict__ xprim,
                                       const short* __restrict__ Wxt,
                                       const float* __restrict__ b,
                                       float* __restrict__ xw, int nTiles,
                                       int tile0, int tstride, short* Asm,
                                       short* Bsm) {
  const int tid = threadIdx.x;
  const int lane = tid & 63, wv = tid >> 6;
  const int wm = wv >> 1, wn = wv & 1;
  const int sslot = (lane & 3) ^ ((lane >> 3) & 3);
  for (int tile = tile0; tile < nTiles; tile += tstride) {
    int tm = tile >> 4, tn = tile & 15;
    int m0 = tm << 7, n0 = tn << 7;
    f32x4 acc[4][4];
    for (int i = 0; i < 4; ++i)
      for (int j = 0; j < 4; ++j) acc[i][j] = (f32x4){0.f, 0.f, 0.f, 0.f};
    for (int kk = 0; kk < 48; ++kk) {
      int ac = (kk < 16 ? kk : kk - 16) << 5;
      int bc = (kk < 32 ? kk : kk - 32) << 5;
      __syncthreads();
      {
        const short* sa =
            xprim + (size_t)(m0 + wv * 32 + (lane >> 2)) * K1 + ac + sslot * 8;
        gl_lds16(sa, Asm + (wv * 32) * 32);
        gl_lds16(sa + (size_t)16 * K1, Asm + (wv * 32 + 16) * 32);
        const short* sb =
            Wxt + (size_t)(n0 + wv * 32 + (lane >> 2)) * K1 + bc + sslot * 8;
        gl_lds16(sb, Bsm + (wv * 32) * 32);
        gl_lds16(sb + (size_t)16 * K1, Bsm + (wv * 32 + 16) * 32);
      }
      __syncthreads();
      bf16x8 af[4], bfr[4];
      for (int mi = 0; mi < 4; ++mi) {
        int R = wm * 64 + mi * 16 + (lane & 15);
        int rs = ((lane >> 4) & 3) ^ ((R >> 1) & 3);
        af[mi] = *(const bf16x8*)(Asm + R * 32 + rs * 8);
      }
      for (int ni = 0; ni < 4; ++ni) {
        int R = wn * 64 + ni * 16 + (lane & 15);
        int rs = ((lane >> 4) & 3) ^ ((R >> 1) & 3);
        bfr[ni] = *(const bf16x8*)(Bsm + R * 32 + rs * 8);
      }
      for (int mi = 0; mi < 4; ++mi)
        for (int ni = 0; ni < 4; ++ni)
          acc[mi][ni] = __builtin_amdgcn_mfma_f32_16x16x32_bf16(
              af[mi], bfr[ni], acc[mi][ni], 0, 0, 0);
    }
    for (int ni = 0; ni < 4; ++ni) {
      float bj = b[n0 + wn * 64 + ni * 16 + (lane & 15)];
      for (int mi = 0; mi < 4; ++mi) {
        int mg = m0 + wm * 64 + mi * 16 + ((lane >> 4) << 2);
        float* dst = xw + (size_t)mg * FH + n0 + wn * 64 + ni * 16 + (lane & 15);
        for (int r = 0; r < 4; ++r) dst[(size_t)r * FH] = acc[mi][ni][r] + bj;
      }
    }
  }
}

// Recurrent steps — R8/R9-proven GLOBAL (sc0 sc1) protocol throughout.
// ONLY change vs R9's passing kernel: B(Wh') fragments are preloaded into a
// local register array bW (32 unique; A-lo pass reuses bW[0..15]) instead of
// per-step LDS reads — removes 48 ds_read_b128/wave/step from the LDS pipe.
__device__ __forceinline__ void run_steps(
    int rb, int cg, int t0, int Tc, unsigned& fl, float& creg,
    const short* __restrict__ Wht, short* hbuf0, short* hbuf1,
    const float* __restrict__ xw, float* __restrict__ out, unsigned* arrH,
    unsigned* cdone, int chIdx, short* hst, float (*glds)[16][16]) {
  const int tid = threadIdx.x;
  const int lane = tid & 63, wv = tid >> 6;
  const int row = tid >> 4, col = tid & 15;
  const int n = rb * 16 + row, jh = cg * 16 + col;
  unsigned* myflag = &arrH[rb * 32 + cg];
  unsigned* grp = &arrH[rb * 32];

  // Preload the 32 unique Wh' B-fragments (local array, constant-indexed
  // after unroll -> register-promoted; reloaded per chunk, negligible).
  bf16x8 bW[32];
  {
    const int gcl = wv * 512 + cg * 16 + (lane & 15);
#pragma unroll
    for (int kk = 0; kk < 32; ++kk)
      bW[kk] = *(const bf16x8*)(Wht + (size_t)gcl * K1 + kk * 32 +
                                (lane >> 4) * 8);
  }

  // gate inputs for step 0 (LLC-coherent, compiler-tracked waits)
  const float* xr0 = xw + ((size_t)n) * FH + jh;
  float x0 = ldf_cc(xr0), x1 = ldf_cc(xr0 + 512), x2 = ldf_cc(xr0 + 1024),
        x3 = ldf_cc(xr0 + 1536);

  for (int tl = 0; tl < Tc; ++tl) {
    const int tg = t0 + tl;
    if (wv == 0) {
      int guard = 0;
      for (;;) {
        unsigned v = ldflag(grp + (lane & 31));
        if (__all(v >= fl)) break;
        __builtin_amdgcn_s_sleep(1);
        if (++guard > (1 << 20)) break;
      }
    }
    __syncthreads();
    // group advanced past chunk boundary -> tell helpers
    if (tl == 0 && cg == 0 && tid == 0) stflag(cdone, (unsigned)chIdx);

    const short* hc = (tg & 1) ? hbuf1 : hbuf0;
    short* hn = (tg & 1) ? hbuf0 : hbuf1;

    // stage hi-half: row r=i*4+wv (uniform/instr), octet=lane -> LDS slots
    // lane^(r&7): bijection over 0..63 -> conflict-free writes.
    bf16x8 tmp[4];
#pragma unroll
    for (int i = 0; i < 4; ++i) {
      int r = i * 4 + wv;
      tmp[i] = ld16cc(hc + (size_t)(rb * 16 + r) * K1 + lane * 8);
    }
    asm volatile("s_waitcnt vmcnt(0)" ::: "memory");
    __builtin_amdgcn_sched_barrier(0);
#pragma unroll
    for (int i = 0; i < 4; ++i) {
      int r = i * 4 + wv;
      *(bf16x8*)(hst + r * 512 + ((lane ^ (r & 7)) << 3)) = tmp[i];
    }
    __syncthreads();
    bf16x8 af[16];
#pragma unroll
    for (int kk = 0; kk < 16; ++kk) {
      int c = kk * 4 + (lane >> 4), r = lane & 15;
      af[kk] = *(const bf16x8*)(hst + r * 512 + ((c ^ (r & 7)) << 3));
    }
    __syncthreads();  // hst free for lo

    bf16x8 tlo[4];  // lo-half loads hide under the 32 hi MFMAs
#pragma unroll
    for (int i = 0; i < 4; ++i) {
      int r = i * 4 + wv;
      tlo[i] = ld16cc(hc + (size_t)(rb * 16 + r) * K1 + 512 + lane * 8);
    }
    f32x4 acc0 = {0.f, 0.f, 0.f, 0.f};
    f32x4 acc1 = {0.f, 0.f, 0.f, 0.f};
#pragma unroll
    for (int kk = 0; kk < 32; ++kk) {  // A-hi x (B-hi | B-lo), B from regs
      if (kk & 1)
        acc1 = __builtin_amdgcn_mfma_f32_16x16x32_bf16(af[kk & 15], bW[kk],
                                                       acc1, 0, 0, 0);
      else
        acc0 = __builtin_amdgcn_mfma_f32_16x16x32_bf16(af[kk & 15], bW[kk],
                                                       acc0, 0, 0, 0);
    }
    asm volatile("s_waitcnt vmcnt(0)" ::: "memory");
    __builtin_amdgcn_sched_barrier(0);
#pragma unroll
    for (int i = 0; i < 4; ++i) {
      int r = i * 4 + wv;
      *(bf16x8*)(hst + r * 512 + ((lane ^ (r & 7)) << 3)) = tlo[i];
    }
    __syncthreads();
#pragma unroll
    for (int kk = 0; kk < 16; ++kk) {  // A-lo x B-hi (reuses bW[0..15])
      int c = kk * 4 + (lane >> 4), r = lane & 15;
      bf16x8 al = *(const bf16x8*)(hst + r * 512 + ((c ^ (r & 7)) << 3));
      if (kk & 1)
        acc1 = __builtin_amdgcn_mfma_f32_16x16x32_bf16(al, bW[kk], acc1, 0, 0, 0);
      else
        acc0 = __builtin_amdgcn_mfma_f32_16x16x32_bf16(al, bW[kk], acc0, 0, 0, 0);
    }
    f32x4 a = acc0 + acc1;
    for (int r = 0; r < 4; ++r)
      glds[wv][((lane >> 4) << 2) + r][lane & 15] = a[r];
    __syncthreads();
    float hv;
    {
      float gi = glds[0][row][col] + x0;
      float gf = glds[1][row][col] + x1;
      float go = glds[2][row][col] + x2;
      float gg = glds[3][row][col] + x3;
      float si = sigf(gi), sf = sigf(gf), so = sigf(go);
      float tg2 = tanhft(gg);
      float cn = sf * creg + si * tg2;
      creg = cn;
      hv = so * tanhft(cn);
      unsigned short hi2 = f2bf(hv);
      unsigned short lo2 = f2bf(hv - bf2f(hi2));
      unsigned ohi = (unsigned)__shfl_xor((int)(unsigned)hi2, 1);
      unsigned olo = (unsigned)__shfl_xor((int)(unsigned)lo2, 1);
      if (col & 1)
        st4cc(hn + (size_t)n * K1 + 512 + (jh - 1),
              olo | ((unsigned)lo2 << 16));
      else
        st4cc(hn + (size_t)n * K1 + jh, (unsigned)hi2 | (ohi << 16));
    }
    asm volatile("s_waitcnt vmcnt(0)" ::: "memory");  // h committed to LLC
    __syncthreads();
    if (tid == 0) stflag(myflag, fl + 1);
    out[((size_t)n * T_ + tg) * H_ + jh] = hv;  // plain cached store
    if (tl + 1 < Tc) {  // prefetch next gate inputs (off crit path)
      const float* xr = xw + ((size_t)(tl + 1) * 64 + n) * FH + jh;
      x0 = ldf_cc(xr); x1 = ldf_cc(xr + 512);
      x2 = ldf_cc(xr + 1024); x3 = ldf_cc(xr + 1536);
    }
    ++fl;
  }
}

__global__ void __launch_bounds__(BLK, 1)
lstm_persistent(const float* __restrict__ x, const float* __restrict__ h0,
                const float* __restrict__ Wx, const float* __restrict__ Wh,
                const float* __restrict__ b, float* __restrict__ out,
                void* __restrict__ ws, int Tc) {
  // wlds carries no data (B in registers) but MUST stay allocated to force
  // 1 WG/CU (proven placement/occupancy regime). A consumed LDS read (asm
  // sink) prevents DCE of the allocation — a write alone is removable.
  __shared__ __align__(16) short wlds[64 * K1];
  __shared__ __align__(16) short sbuf[8192];  // 16 KiB: phase1 A/B | h stage
  __shared__ float glds[4][16][16];           // 4 KiB gate exchange

  char* wsb = (char*)ws;
  unsigned* relF   = (unsigned*)(wsb + 0);
  unsigned* chrdy  = (unsigned*)(wsb + 64);   // helper->stepper chunk flag
  unsigned* cdone  = (unsigned*)(wsb + 128);  // [4] stepper->helper progress
  unsigned* arrF   = (unsigned*)(wsb + 256);  // [256]
  unsigned* relJ   = (unsigned*)(wsb + 1280);
  unsigned* arrJ   = (unsigned*)(wsb + 1344); // [128]
  unsigned* arrH   = (unsigned*)(wsb + 2048); // [4][32] step flags
  short* Wxt   = (short*)(wsb + 4096);        // [2048][1024] bf16 hi|lo, W^T
  short* Wht   = Wxt + (size_t)FH * K1;
  short* hbuf0 = Wht + (size_t)FH * K1;       // [64][1024]
  short* hbuf1 = hbuf0 + N_ * K1;
  float* cbuf  = (float*)(hbuf1 + N_ * K1);   // (layout keep)
  short* xprim = (short*)(cbuf + N_ * H_);    // [Tc*64][1024]
  float* xwxb  = (float*)(xprim + (size_t)Tc * N_ * K1);  // 2 x [Tc*64][2048]

  const int tid = threadIdx.x;
  const int wg = blockIdx.x;
  const int gtid = wg * BLK + tid;
  // XCD-interleaved roles (wg%8): steppers on 0-3, helpers on 4-7.
  const bool isStep = (wg & 7) < 4;
  const int rb = wg & 7;                       // group (0..3) when isStep
  const int cg = wg >> 3;                      // 0..31 within group
  const int hid = (wg >> 3) * 4 + ((wg & 7) - 4);  // 0..127 for helpers

  unsigned genF = 0, genJ = 0, fl = 0;

  // LDS-allocation forcer: store + consumed read (cannot be DCE'd).
  wlds[tid * 256] = (short)tid;
  asm volatile("" ::"v"((int)wlds[tid * 256]));

  // ---- prep: split-transpose weights (octet-wise), h0 ----
  for (int idx = gtid; idx < 2 * FH * 64; idx += NWG * BLK) {
    int m = idx >> 17;
    int rr = idx & 131071;
    int j = rr >> 6;
    int oct = rr & 63;
    const float* W = m ? Wh : Wx;
    bf16x8 hv, lv;
#pragma unroll
    for (int i = 0; i < 8; ++i) {
      float v = W[(size_t)(oct * 8 + i) * FH + j];
      unsigned short h = f2bf(v);
      hv[i] = (short)h;
      lv[i] = (short)f2bf(v - bf2f(h));
    }
    short* dst = m ? Wht : Wxt;
    *(bf16x8*)(dst + (size_t)j * K1 + oct * 8) = hv;
    *(bf16x8*)(dst + (size_t)j * K1 + 512 + oct * 8) = lv;
  }
  for (int idx = gtid; idx < N_ * H_; idx += NWG * BLK) {
    int n = idx >> 9, k = idx & 511;
    float v = h0[idx];
    unsigned short hi = f2bf(v);
    unsigned short lo = f2bf(v - bf2f(hi));
    hbuf0[n * K1 + k] = (short)hi;
    hbuf0[n * K1 + 512 + k] = (short)lo;
  }
  gbar2<4>(arrF, relF, ++genF, wg);

  const int nCh = T_ / Tc;
  const int Mch = Tc * N_;
  const int nTiles = (Mch >> 7) * (FH >> 7);
  const size_t xwStride = (size_t)Mch * FH;

  // ---- chunk 0 front work (all WGs) ----
  convert_x(x, xprim, 0, Mch, gtid, NWG * BLK);
  gbar2<2>(arrF, relF, ++genF, wg);
  phase1(xprim, Wxt, b, xwxb, nTiles, wg, NWG, sbuf, sbuf + 4096);
  gbar2<2>(arrF, relF, ++genF, wg);

  if (isStep) {
    float creg = 0.0f;
    for (int ch = 0; ch < nCh; ++ch) {
      if (ch > 0) {
        if (tid == 0) {
          int guard = 0;
          while (ldflag(chrdy) < (unsigned)ch) {
            __builtin_amdgcn_s_sleep(8);
            if (++guard > (1 << 20)) break;
          }
        }
        __syncthreads();  // no fence: xw read via LLC-coherent loads
      }
      run_steps(rb, cg, ch * Tc, Tc, fl, creg, Wht, hbuf0, hbuf1,
                xwxb + (size_t)(ch & 1) * xwStride, out, arrH, &cdone[rb], ch,
                sbuf, glds);
    }
  } else {
    // helpers: produce xwxb[ch+1] while steppers run ch; gate on cdone
    for (int ch = 0; ch + 1 < nCh; ++ch) {
      if (ch > 0) {
        if (tid == 0) {
          int guard = 0;
          for (;;) {
            unsigned d0 = ldflag(&cdone[0]);
            unsigned d1 = ldflag(&cdone[1]);
            unsigned d2 = ldflag(&cdone[2]);
            unsigned d3 = ldflag(&cdone[3]);
            if (d0 >= (unsigned)ch && d1 >= (unsigned)ch &&
                d2 >= (unsigned)ch && d3 >= (unsigned)ch)
              break;
            __builtin_amdgcn_s_sleep(16);
            if (++guard > (1 << 20)) break;
          }
        }
        __syncthreads();
      }
      convert_x(x, xprim, (ch + 1) * Tc, Mch, hid * BLK + tid, NHELP * BLK);
      hbar<1>(arrJ, relJ, ++genJ, hid);
      phase1(xprim, Wxt, b, xwxb + (size_t)((ch + 1) & 1) * xwStride, nTiles,
             hid, NHELP, sbuf, sbuf + 4096);
      hbar<1>(arrJ, relJ, ++genJ, hid);  // release fences flush phase1 writes
      if (hid == 0 && tid == 0) stflag(chrdy, (unsigned)(ch + 1));
    }
  }
}

extern "C" void kernel_launch(void* const* d_in, const int* in_sizes, int n_in,
                              void* d_out, int out_size, void* d_ws, size_t ws_size,
                              hipStream_t stream) {
  (void)in_sizes; (void)n_in; (void)out_size;
  const float* x  = (const float*)d_in[0];
  const float* h0 = (const float*)d_in[1];
  const float* Wx = (const float*)d_in[2];
  const float* Wh = (const float*)d_in[3];
  const float* b  = (const float*)d_in[4];
  float* out = (float*)d_out;

  size_t fixed = 4096 + 2 * (size_t)FH * K1 * 2 + 2 * (size_t)N_ * K1 * 2 +
                 (size_t)N_ * H_ * 4;
  size_t perTc = (size_t)N_ * K1 * 2 + 2 * (size_t)N_ * FH * 4;
  int Tc = 64;
  while (Tc > 1 && fixed + (size_t)Tc * perTc > ws_size) Tc >>= 1;

  (void)hipMemsetAsync(d_ws, 0, 4096, stream);  // reset barriers every replay

  void* args[] = {(void*)&x, (void*)&h0, (void*)&Wx, (void*)&Wh,
                  (void*)&b, (void*)&out, (void*)&d_ws, (void*)&Tc};

  // Path A: cooperative launch (static 148 KiB LDS -> 1 WG/CU, 256 WGs fit).
  hipError_t e = hipLaunchCooperativeKernel((void*)lstm_persistent, dim3(NWG),
                                            dim3(BLK), args, 0, stream);
  if (e != hipSuccess) {
    // Path B: plain launch (custom barriers only need co-residency).
    (void)hipGetLastError();
    lstm_persistent<<<dim3(NWG), dim3(BLK), 0, stream>>>(x, h0, Wx, Wh, b,
                                                         out, d_ws, Tc);
    (void)hipGetLastError();
  }
}

// Round 13
// 1788.133 us; speedup vs baseline: 1.3706x; 1.0687x over previous
//
#include <hip/hip_runtime.h>
#include <hip/hip_bf16.h>

#define N_  64
#define T_  512
#define D_  512
#define H_  512
#define FH  2048   // 4H
#define K1  1024   // hi|lo packed columns
#define NWG 256
#define NSTEP 128
#define NHELP 128
#define BLK 256

typedef __attribute__((ext_vector_type(4))) float f32x4;
typedef __attribute__((ext_vector_type(8))) short bf16x8;

__device__ __forceinline__ unsigned short f2bf(float f) {
  unsigned u = __float_as_uint(f);
  return (unsigned short)((u + 0x7FFFu + ((u >> 16) & 1u)) >> 16);
}
__device__ __forceinline__ float bf2f(unsigned short s) {
  return __uint_as_float(((unsigned)s) << 16);
}
__device__ __forceinline__ float sigf(float x) {
  return 1.0f / (1.0f + __expf(-x));
}
__device__ __forceinline__ float tanhft(float x) {  // branch-free tanh
  x = fminf(15.f, fmaxf(-15.f, x));
  float e = __expf(2.f * x);
  return (e - 1.f) / (e + 1.f);
}

__device__ __forceinline__ void gl_lds16(const void* g, void* l) {
  __builtin_amdgcn_global_load_lds(
      (const __attribute__((address_space(1))) void*)g,
      (__attribute__((address_space(3))) void*)l, 16, 0, 0);
}

// LLC-coherent ops (sc0 sc1): the proven cross-XCD handoff path.
__device__ __forceinline__ bf16x8 ld16cc(const short* p) {
  bf16x8 d;
  asm volatile("global_load_dwordx4 %0, %1, off sc0 sc1" : "=v"(d) : "v"(p));
  return d;
}
__device__ __forceinline__ void st4cc(short* p, unsigned v) {
  asm volatile("global_store_dword %0, %1, off sc0 sc1" ::"v"(p), "v"(v)
               : "memory");
}
__device__ __forceinline__ unsigned ldflag(const unsigned* p) {
  unsigned v;  // embedded waitcnt: value valid on return (rule-18 safe)
  asm volatile("global_load_dword %0, %1, off sc0 sc1\ns_waitcnt vmcnt(0)"
               : "=v"(v) : "v"(p) : "memory");
  return v;
}
__device__ __forceinline__ void stflag(unsigned* p, unsigned v) {
  asm volatile("global_store_dword %0, %1, off sc0 sc1" ::"v"(p), "v"(v)
               : "memory");
}
// LLC-coherent float load, compiler-tracked waitcnt (xw gate inputs).
__device__ __forceinline__ float ldf_cc(const float* p) {
  return __hip_atomic_load(p, __ATOMIC_RELAXED, __HIP_MEMORY_SCOPE_AGENT);
}

// Grid barrier over 256 WGs (prologue only).
template <int SLP>
__device__ __forceinline__ void gbar2(unsigned* arr, unsigned* rel,
                                      unsigned gen, int wg) {
  __syncthreads();
  const int tid = threadIdx.x;
  if (tid == 0) {
    __builtin_amdgcn_fence(__ATOMIC_RELEASE, "agent");
    __hip_atomic_store(&arr[wg], gen, __ATOMIC_RELAXED,
                       __HIP_MEMORY_SCOPE_AGENT);
  }
  if (wg == 0) {
    if (tid < 64) {
      int guard = 0;
      for (;;) {
        unsigned v0 = __hip_atomic_load(&arr[tid], __ATOMIC_RELAXED,
                                        __HIP_MEMORY_SCOPE_AGENT);
        unsigned v1 = __hip_atomic_load(&arr[tid + 64], __ATOMIC_RELAXED,
                                        __HIP_MEMORY_SCOPE_AGENT);
        unsigned v2 = __hip_atomic_load(&arr[tid + 128], __ATOMIC_RELAXED,
                                        __HIP_MEMORY_SCOPE_AGENT);
        unsigned v3 = __hip_atomic_load(&arr[tid + 192], __ATOMIC_RELAXED,
                                        __HIP_MEMORY_SCOPE_AGENT);
        if (__all(v0 >= gen && v1 >= gen && v2 >= gen && v3 >= gen)) break;
        __builtin_amdgcn_s_sleep(SLP);
        if (++guard > (1 << 20)) break;
      }
    }
    __syncthreads();
    if (tid == 0)
      __hip_atomic_store(rel, gen, __ATOMIC_RELAXED, __HIP_MEMORY_SCOPE_AGENT);
  } else if (tid == 0) {
    int guard = 0;
    while (__hip_atomic_load(rel, __ATOMIC_RELAXED,
                             __HIP_MEMORY_SCOPE_AGENT) < gen) {
      __builtin_amdgcn_s_sleep(SLP);
      if (++guard > (1 << 20)) break;
    }
  }
  if (tid == 0) __builtin_amdgcn_fence(__ATOMIC_ACQUIRE, "agent");
  __syncthreads();
}

// Helper-group barrier (128 helper WGs); poller hid==0.
template <int SLP>
__device__ __forceinline__ void hbar(unsigned* arr, unsigned* rel,
                                     unsigned gen, int hid) {
  __syncthreads();
  const int tid = threadIdx.x;
  if (tid == 0) {
    __builtin_amdgcn_fence(__ATOMIC_RELEASE, "agent");
    __hip_atomic_store(&arr[hid], gen, __ATOMIC_RELAXED,
                       __HIP_MEMORY_SCOPE_AGENT);
  }
  if (hid == 0) {
    if (tid < 64) {
      int guard = 0;
      for (;;) {
        unsigned v0 = __hip_atomic_load(&arr[tid], __ATOMIC_RELAXED,
                                        __HIP_MEMORY_SCOPE_AGENT);
        unsigned v1 = __hip_atomic_load(&arr[tid + 64], __ATOMIC_RELAXED,
                                        __HIP_MEMORY_SCOPE_AGENT);
        if (__all(v0 >= gen && v1 >= gen)) break;
        __builtin_amdgcn_s_sleep(SLP);
        if (++guard > (1 << 20)) break;
      }
    }
    __syncthreads();
    if (tid == 0)
      __hip_atomic_store(rel, gen, __ATOMIC_RELAXED, __HIP_MEMORY_SCOPE_AGENT);
  } else if (tid == 0) {
    int guard = 0;
    while (__hip_atomic_load(rel, __ATOMIC_RELAXED,
                             __HIP_MEMORY_SCOPE_AGENT) < gen) {
      __builtin_amdgcn_s_sleep(SLP);
      if (++guard > (1 << 20)) break;
    }
  }
  if (tid == 0) __builtin_amdgcn_fence(__ATOMIC_ACQUIRE, "agent");
  __syncthreads();
}

// x chunk -> hi/lo bf16 (octet-wise coalesced)
__device__ __forceinline__ void convert_x(const float* __restrict__ x,
                                          short* __restrict__ xprim, int t0,
                                          int Mch, int idx0, int stride) {
  for (int idx = idx0; idx < Mch * 64; idx += stride) {
    int mrow = idx >> 6, oct = idx & 63;
    int tl = mrow >> 6, n = mrow & 63;
    const float* src = x + ((size_t)n * T_ + (t0 + tl)) * D_ + oct * 8;
    bf16x8 hv, lv;
#pragma unroll
    for (int i = 0; i < 8; ++i) {
      float v = src[i];
      unsigned short h = f2bf(v);
      hv[i] = (short)h;
      lv[i] = (short)f2bf(v - bf2f(h));
    }
    *(bf16x8*)(xprim + (size_t)mrow * K1 + oct * 8) = hv;
    *(bf16x8*)(xprim + (size_t)mrow * K1 + 512 + oct * 8) = lv;
  }
}

// Phase-1 GEMM: xw = x' @ Wx' + b (128x128 tiles, K'=1536, split-bf16)
__device__ __forceinline__ void phase1(const short* __restrict__ xprim,
                                       const short* __restrict__ Wxt,
                                       const float* __restrict__ b,
                                       float* __restrict__ xw, int nTiles,
                                       int tile0, int tstride, short* Asm,
                                       short* Bsm) {
  const int tid = threadIdx.x;
  const int lane = tid & 63, wv = tid >> 6;
  const int wm = wv >> 1, wn = wv & 1;
  const int sslot = (lane & 3) ^ ((lane >> 3) & 3);
  for (int tile = tile0; tile < nTiles; tile += tstride) {
    int tm = tile >> 4, tn = tile & 15;
    int m0 = tm << 7, n0 = tn << 7;
    f32x4 acc[4][4];
    for (int i = 0; i < 4; ++i)
      for (int j = 0; j < 4; ++j) acc[i][j] = (f32x4){0.f, 0.f, 0.f, 0.f};
    for (int kk = 0; kk < 48; ++kk) {
      int ac = (kk < 16 ? kk : kk - 16) << 5;
      int bc = (kk < 32 ? kk : kk - 32) << 5;
      __syncthreads();
      {
        const short* sa =
            xprim + (size_t)(m0 + wv * 32 + (lane >> 2)) * K1 + ac + sslot * 8;
        gl_lds16(sa, Asm + (wv * 32) * 32);
        gl_lds16(sa + (size_t)16 * K1, Asm + (wv * 32 + 16) * 32);
        const short* sb =
            Wxt + (size_t)(n0 + wv * 32 + (lane >> 2)) * K1 + bc + sslot * 8;
        gl_lds16(sb, Bsm + (wv * 32) * 32);
        gl_lds16(sb + (size_t)16 * K1, Bsm + (wv * 32 + 16) * 32);
      }
      __syncthreads();
      bf16x8 af[4], bfr[4];
      for (int mi = 0; mi < 4; ++mi) {
        int R = wm * 64 + mi * 16 + (lane & 15);
        int rs = ((lane >> 4) & 3) ^ ((R >> 1) & 3);
        af[mi] = *(const bf16x8*)(Asm + R * 32 + rs * 8);
      }
      for (int ni = 0; ni < 4; ++ni) {
        int R = wn * 64 + ni * 16 + (lane & 15);
        int rs = ((lane >> 4) & 3) ^ ((R >> 1) & 3);
        bfr[ni] = *(const bf16x8*)(Bsm + R * 32 + rs * 8);
      }
      for (int mi = 0; mi < 4; ++mi)
        for (int ni = 0; ni < 4; ++ni)
          acc[mi][ni] = __builtin_amdgcn_mfma_f32_16x16x32_bf16(
              af[mi], bfr[ni], acc[mi][ni], 0, 0, 0);
    }
    for (int ni = 0; ni < 4; ++ni) {
      float bj = b[n0 + wn * 64 + ni * 16 + (lane & 15)];
      for (int mi = 0; mi < 4; ++mi) {
        int mg = m0 + wm * 64 + mi * 16 + ((lane >> 4) << 2);
        float* dst = xw + (size_t)mg * FH + n0 + wn * 64 + ni * 16 + (lane & 15);
        for (int r = 0; r < 4; ++r) dst[(size_t)r * FH] = acc[mi][ni][r] + bj;
      }
    }
  }
}

// Recurrent steps — R12-proven skeleton; ONLY change: hi+lo h staged into one
// 32KB LDS buffer in a single burst (one vmcnt, no mid-step drain/syncs).
// B(Wh') fragments in registers (bW, 32 unique; A-lo pass reuses bW[0..15]).
__device__ __forceinline__ void run_steps(
    int rb, int cg, int t0, int Tc, unsigned& fl, float& creg,
    const short* __restrict__ Wht, short* hbuf0, short* hbuf1,
    const float* __restrict__ xw, float* __restrict__ out, unsigned* arrH,
    unsigned* cdone, int chIdx, short* hst, float (*glds)[16][16]) {
  const int tid = threadIdx.x;
  const int lane = tid & 63, wv = tid >> 6;
  const int row = tid >> 4, col = tid & 15;
  const int n = rb * 16 + row, jh = cg * 16 + col;
  unsigned* myflag = &arrH[rb * 32 + cg];
  unsigned* grp = &arrH[rb * 32];
  short* hstLo = hst + 16 * 512;  // lo half lives at +16KB (no buffer reuse)

  // Preload the 32 unique Wh' B-fragments (register-promoted).
  bf16x8 bW[32];
  {
    const int gcl = wv * 512 + cg * 16 + (lane & 15);
#pragma unroll
    for (int kk = 0; kk < 32; ++kk)
      bW[kk] = *(const bf16x8*)(Wht + (size_t)gcl * K1 + kk * 32 +
                                (lane >> 4) * 8);
  }

  // gate inputs for step 0 (LLC-coherent, compiler-tracked waits)
  const float* xr0 = xw + ((size_t)n) * FH + jh;
  float x0 = ldf_cc(xr0), x1 = ldf_cc(xr0 + 512), x2 = ldf_cc(xr0 + 1024),
        x3 = ldf_cc(xr0 + 1536);

  for (int tl = 0; tl < Tc; ++tl) {
    const int tg = t0 + tl;
    if (wv == 0) {
      int guard = 0;
      for (;;) {
        unsigned v = ldflag(grp + (lane & 31));
        if (__all(v >= fl)) break;
        __builtin_amdgcn_s_sleep(1);
        if (++guard > (1 << 20)) break;
      }
    }
    __syncthreads();
    // group advanced past chunk boundary -> tell helpers
    if (tl == 0 && cg == 0 && tid == 0) stflag(cdone, (unsigned)chIdx);

    const short* hc = (tg & 1) ? hbuf1 : hbuf0;
    short* hn = (tg & 1) ? hbuf0 : hbuf1;

    // ---- stage BOTH halves in one burst: row r=i*4+wv (uniform/instr),
    // octet=lane; LDS slots lane^(r&7): bijection -> conflict-free writes.
    bf16x8 tmp[8];
#pragma unroll
    for (int i = 0; i < 4; ++i) {
      int r = i * 4 + wv;
      tmp[i] = ld16cc(hc + (size_t)(rb * 16 + r) * K1 + lane * 8);
    }
#pragma unroll
    for (int i = 0; i < 4; ++i) {
      int r = i * 4 + wv;
      tmp[4 + i] = ld16cc(hc + (size_t)(rb * 16 + r) * K1 + 512 + lane * 8);
    }
    asm volatile("s_waitcnt vmcnt(0)" ::: "memory");
    __builtin_amdgcn_sched_barrier(0);
#pragma unroll
    for (int i = 0; i < 4; ++i) {
      int r = i * 4 + wv;
      *(bf16x8*)(hst + r * 512 + ((lane ^ (r & 7)) << 3)) = tmp[i];
      *(bf16x8*)(hstLo + r * 512 + ((lane ^ (r & 7)) << 3)) = tmp[4 + i];
    }
    __syncthreads();

    bf16x8 af[16];
#pragma unroll
    for (int kk = 0; kk < 16; ++kk) {
      int c = kk * 4 + (lane >> 4), r = lane & 15;
      af[kk] = *(const bf16x8*)(hst + r * 512 + ((c ^ (r & 7)) << 3));
    }
    f32x4 acc0 = {0.f, 0.f, 0.f, 0.f};
    f32x4 acc1 = {0.f, 0.f, 0.f, 0.f};
#pragma unroll
    for (int kk = 0; kk < 32; ++kk) {  // A-hi x (B-hi | B-lo), B from regs
      if (kk & 1)
        acc1 = __builtin_amdgcn_mfma_f32_16x16x32_bf16(af[kk & 15], bW[kk],
                                                       acc1, 0, 0, 0);
      else
        acc0 = __builtin_amdgcn_mfma_f32_16x16x32_bf16(af[kk & 15], bW[kk],
                                                       acc0, 0, 0, 0);
    }
#pragma unroll
    for (int kk = 0; kk < 16; ++kk) {  // A-lo x B-hi (reuses bW[0..15])
      int c = kk * 4 + (lane >> 4), r = lane & 15;
      bf16x8 al = *(const bf16x8*)(hstLo + r * 512 + ((c ^ (r & 7)) << 3));
      if (kk & 1)
        acc1 = __builtin_amdgcn_mfma_f32_16x16x32_bf16(al, bW[kk], acc1, 0, 0, 0);
      else
        acc0 = __builtin_amdgcn_mfma_f32_16x16x32_bf16(al, bW[kk], acc0, 0, 0, 0);
    }
    f32x4 a = acc0 + acc1;
    for (int r = 0; r < 4; ++r)
      glds[wv][((lane >> 4) << 2) + r][lane & 15] = a[r];
    __syncthreads();
    float hv;
    {
      float gi = glds[0][row][col] + x0;
      float gf = glds[1][row][col] + x1;
      float go = glds[2][row][col] + x2;
      float gg = glds[3][row][col] + x3;
      float si = sigf(gi), sf = sigf(gf), so = sigf(go);
      float tg2 = tanhft(gg);
      float cn = sf * creg + si * tg2;
      creg = cn;
      hv = so * tanhft(cn);
      unsigned short hi2 = f2bf(hv);
      unsigned short lo2 = f2bf(hv - bf2f(hi2));
      unsigned ohi = (unsigned)__shfl_xor((int)(unsigned)hi2, 1);
      unsigned olo = (unsigned)__shfl_xor((int)(unsigned)lo2, 1);
      if (col & 1)
        st4cc(hn + (size_t)n * K1 + 512 + (jh - 1),
              olo | ((unsigned)lo2 << 16));
      else
        st4cc(hn + (size_t)n * K1 + jh, (unsigned)hi2 | (ohi << 16));
    }
    asm volatile("s_waitcnt vmcnt(0)" ::: "memory");  // h committed to LLC
    __syncthreads();
    if (tid == 0) stflag(myflag, fl + 1);
    out[((size_t)n * T_ + tg) * H_ + jh] = hv;  // plain cached store
    if (tl + 1 < Tc) {  // prefetch next gate inputs (off crit path)
      const float* xr = xw + ((size_t)(tl + 1) * 64 + n) * FH + jh;
      x0 = ldf_cc(xr); x1 = ldf_cc(xr + 512);
      x2 = ldf_cc(xr + 1024); x3 = ldf_cc(xr + 1536);
    }
    ++fl;
  }
}

__global__ void __launch_bounds__(BLK, 1)
lstm_persistent(const float* __restrict__ x, const float* __restrict__ h0,
                const float* __restrict__ Wx, const float* __restrict__ Wh,
                const float* __restrict__ b, float* __restrict__ out,
                void* __restrict__ ws, int Tc) {
  // sbuf: phase1 Asm/Bsm (16 KiB) OR step h-stage hi+lo (32 KiB)
  __shared__ __align__(16) short sbuf[16384];
  __shared__ float glds[4][16][16];           // 4 KiB gate exchange

  char* wsb = (char*)ws;
  unsigned* relF   = (unsigned*)(wsb + 0);
  unsigned* chrdy  = (unsigned*)(wsb + 64);   // helper->stepper chunk flag
  unsigned* cdone  = (unsigned*)(wsb + 128);  // [4] stepper->helper progress
  unsigned* arrF   = (unsigned*)(wsb + 256);  // [256]
  unsigned* relJ   = (unsigned*)(wsb + 1280);
  unsigned* arrJ   = (unsigned*)(wsb + 1344); // [128]
  unsigned* arrH   = (unsigned*)(wsb + 2048); // [4][32] step flags
  short* Wxt   = (short*)(wsb + 4096);        // [2048][1024] bf16 hi|lo, W^T
  short* Wht   = Wxt + (size_t)FH * K1;
  short* hbuf0 = Wht + (size_t)FH * K1;       // [64][1024]
  short* hbuf1 = hbuf0 + N_ * K1;
  float* cbuf  = (float*)(hbuf1 + N_ * K1);   // (layout keep)
  short* xprim = (short*)(cbuf + N_ * H_);    // [Tc*64][1024]
  float* xwxb  = (float*)(xprim + (size_t)Tc * N_ * K1);  // 2 x [Tc*64][2048]

  const int tid = threadIdx.x;
  const int wg = blockIdx.x;
  const int gtid = wg * BLK + tid;
  // XCD-interleaved roles (wg%8): steppers on 0-3, helpers on 4-7.
  const bool isStep = (wg & 7) < 4;
  const int rb = wg & 7;                       // group (0..3) when isStep
  const int cg = wg >> 3;                      // 0..31 within group
  const int hid = (wg >> 3) * 4 + ((wg & 7) - 4);  // 0..127 for helpers

  unsigned genF = 0, genJ = 0, fl = 0;

  // ---- prep: split-transpose weights (octet-wise), h0 ----
  for (int idx = gtid; idx < 2 * FH * 64; idx += NWG * BLK) {
    int m = idx >> 17;
    int rr = idx & 131071;
    int j = rr >> 6;
    int oct = rr & 63;
    const float* W = m ? Wh : Wx;
    bf16x8 hv, lv;
#pragma unroll
    for (int i = 0; i < 8; ++i) {
      float v = W[(size_t)(oct * 8 + i) * FH + j];
      unsigned short h = f2bf(v);
      hv[i] = (short)h;
      lv[i] = (short)f2bf(v - bf2f(h));
    }
    short* dst = m ? Wht : Wxt;
    *(bf16x8*)(dst + (size_t)j * K1 + oct * 8) = hv;
    *(bf16x8*)(dst + (size_t)j * K1 + 512 + oct * 8) = lv;
  }
  for (int idx = gtid; idx < N_ * H_; idx += NWG * BLK) {
    int n = idx >> 9, k = idx & 511;
    float v = h0[idx];
    unsigned short hi = f2bf(v);
    unsigned short lo = f2bf(v - bf2f(hi));
    hbuf0[n * K1 + k] = (short)hi;
    hbuf0[n * K1 + 512 + k] = (short)lo;
  }
  gbar2<4>(arrF, relF, ++genF, wg);

  const int nCh = T_ / Tc;
  const int Mch = Tc * N_;
  const int nTiles = (Mch >> 7) * (FH >> 7);
  const size_t xwStride = (size_t)Mch * FH;

  // ---- chunk 0 front work (all WGs) ----
  convert_x(x, xprim, 0, Mch, gtid, NWG * BLK);
  gbar2<2>(arrF, relF, ++genF, wg);
  phase1(xprim, Wxt, b, xwxb, nTiles, wg, NWG, sbuf, sbuf + 4096);
  gbar2<2>(arrF, relF, ++genF, wg);

  if (isStep) {
    float creg = 0.0f;
    for (int ch = 0; ch < nCh; ++ch) {
      if (ch > 0) {
        if (tid == 0) {
          int guard = 0;
          while (ldflag(chrdy) < (unsigned)ch) {
            __builtin_amdgcn_s_sleep(8);
            if (++guard > (1 << 20)) break;
          }
        }
        __syncthreads();  // no fence: xw read via LLC-coherent loads
      }
      run_steps(rb, cg, ch * Tc, Tc, fl, creg, Wht, hbuf0, hbuf1,
                xwxb + (size_t)(ch & 1) * xwStride, out, arrH, &cdone[rb], ch,
                sbuf, glds);
    }
  } else {
    // helpers: produce xwxb[ch+1] while steppers run ch; gate on cdone
    for (int ch = 0; ch + 1 < nCh; ++ch) {
      if (ch > 0) {
        if (tid == 0) {
          int guard = 0;
          for (;;) {
            unsigned d0 = ldflag(&cdone[0]);
            unsigned d1 = ldflag(&cdone[1]);
            unsigned d2 = ldflag(&cdone[2]);
            unsigned d3 = ldflag(&cdone[3]);
            if (d0 >= (unsigned)ch && d1 >= (unsigned)ch &&
                d2 >= (unsigned)ch && d3 >= (unsigned)ch)
              break;
            __builtin_amdgcn_s_sleep(16);
            if (++guard > (1 << 20)) break;
          }
        }
        __syncthreads();
      }
      convert_x(x, xprim, (ch + 1) * Tc, Mch, hid * BLK + tid, NHELP * BLK);
      hbar<1>(arrJ, relJ, ++genJ, hid);
      phase1(xprim, Wxt, b, xwxb + (size_t)((ch + 1) & 1) * xwStride, nTiles,
             hid, NHELP, sbuf, sbuf + 4096);
      hbar<1>(arrJ, relJ, ++genJ, hid);  // release fences flush phase1 writes
      if (hid == 0 && tid == 0) stflag(chrdy, (unsigned)(ch + 1));
    }
  }
}

extern "C" void kernel_launch(void* const* d_in, const int* in_sizes, int n_in,
                              void* d_out, int out_size, void* d_ws, size_t ws_size,
                              hipStream_t stream) {
  (void)in_sizes; (void)n_in; (void)out_size;
  const float* x  = (const float*)d_in[0];
  const float* h0 = (const float*)d_in[1];
  const float* Wx = (const float*)d_in[2];
  const float* Wh = (const float*)d_in[3];
  const float* b  = (const float*)d_in[4];
  float* out = (float*)d_out;

  size_t fixed = 4096 + 2 * (size_t)FH * K1 * 2 + 2 * (size_t)N_ * K1 * 2 +
                 (size_t)N_ * H_ * 4;
  size_t perTc = (size_t)N_ * K1 * 2 + 2 * (size_t)N_ * FH * 4;
  int Tc = 64;
  while (Tc > 1 && fixed + (size_t)Tc * perTc > ws_size) Tc >>= 1;

  (void)hipMemsetAsync(d_ws, 0, 4096, stream);  // reset barriers every replay

  void* args[] = {(void*)&x, (void*)&h0, (void*)&Wx, (void*)&Wh,
                  (void*)&b, (void*)&out, (void*)&d_ws, (void*)&Tc};

  // Path A: cooperative launch; Path B: plain (barriers only need
  // co-residency, empirically satisfied at grid=256=#CUs — R12).
  hipError_t e = hipLaunchCooperativeKernel((void*)lstm_persistent, dim3(NWG),
                                            dim3(BLK), args, 0, stream);
  if (e != hipSuccess) {
    (void)hipGetLastError();
    lstm_persistent<<<dim3(NWG), dim3(BLK), 0, stream>>>(x, h0, Wx, Wh, b,
                                                         out, d_ws, Tc);
    (void)hipGetLastError();
  }
}